// Round 2
// 396.155 us; speedup vs baseline: 1.0019x; 1.0019x over previous
//
#include <hip/hip_runtime.h>

typedef unsigned short u16;
typedef unsigned int u32;
typedef unsigned char u8;

typedef __attribute__((ext_vector_type(8))) short bf16x8;
typedef __attribute__((ext_vector_type(4))) short bf16x4;
typedef __attribute__((ext_vector_type(4))) float f32x4;

__device__ __forceinline__ float bf2f(u16 u) {
    union { u32 i; float f; } v; v.i = ((u32)u) << 16; return v.f;
}
__device__ __forceinline__ u16 f2bf(float f) {
    union { float f; u32 i; } v; v.f = f;
    u32 r = v.i + 0x7fffu + ((v.i >> 16) & 1u);
    return (u16)(r >> 16);
}
// pack two f32 -> bf16x2 in one u32 (low = a, high = b)
__device__ __forceinline__ u32 pkbf(float a, float b) {
#if __has_builtin(__builtin_amdgcn_cvt_pk_bf16_f32)
    auto r = __builtin_amdgcn_cvt_pk_bf16_f32(a, b);
    u32 u; __builtin_memcpy(&u, &r, 4); return u;
#else
    return (u32)f2bf(a) | ((u32)f2bf(b) << 16);
#endif
}

// async global->LDS, 16B per lane; lds must be wave-uniform (lane*16 added by HW)
__device__ __forceinline__ void async16(u16* lds, const u16* g) {
    __builtin_amdgcn_global_load_lds(
        (const __attribute__((address_space(1))) void*)g,
        (__attribute__((address_space(3))) void*)lds, 16, 0, 0);
}

// ------------------------------------------------------------- dtype detect
__global__ __launch_bounds__(256) void detect_dtype(const u32* __restrict__ x,
                                                    int* __restrict__ flag) {
    int tid = threadIdx.x;
    int hits = 0;
    for (int i = 0; i < 4; ++i) {
        u32 w = x[tid * 4 + i];
        u32 e = (w >> 7) & 0xFFu;
        hits += (e >= 110u && e <= 131u) ? 1 : 0;
    }
    for (int off = 1; off < 64; off <<= 1) hits += __shfl_xor(hits, off, 64);
    __shared__ int red[4];
    int wave = tid >> 6, lane = tid & 63;
    if (lane == 0) red[wave] = hits;
    __syncthreads();
    if (tid == 0) flag[0] = (red[0] + red[1] + red[2] + red[3] > 512) ? 1 : 0;
}

// ------------------------------------------------------------- convert pass
__global__ __launch_bounds__(256) void conv_bf16(const void* __restrict__ src,
                                                 u16* __restrict__ dst,
                                                 const int* __restrict__ flagp) {
    int flag = *flagp;
    size_t i = (size_t)blockIdx.x * 256 + threadIdx.x;
    if (flag) {
        ((uint4*)dst)[i] = ((const uint4*)src)[i];
    } else {
        const float4* s = (const float4*)src + i * 2;
        float4 f0 = s[0], f1 = s[1];
        u16 t[8];
        t[0] = f2bf(f0.x); t[1] = f2bf(f0.y); t[2] = f2bf(f0.z); t[3] = f2bf(f0.w);
        t[4] = f2bf(f1.x); t[5] = f2bf(f1.y); t[6] = f2bf(f1.z); t[7] = f2bf(f1.w);
        ((uint4*)dst)[i] = *(const uint4*)t;
    }
}

// ------------------------------------------------------------- mask pack
__global__ __launch_bounds__(256) void mask_pack(const int* __restrict__ m,
                                                 u8* __restrict__ o) {
    size_t i = (size_t)blockIdx.x * 256 + threadIdx.x;
    const int4* mp = (const int4*)m + i * 4;
    uint4 out;
    u32* op = (u32*)&out;
    for (int j = 0; j < 4; ++j) {
        int4 a = mp[j];
        op[j] = (a.x == 0 ? 0xFFu : 0u) | (a.y == 0 ? 0xFF00u : 0u) |
                (a.z == 0 ? 0xFF0000u : 0u) | (a.w == 0 ? 0xFF000000u : 0u);
    }
    ((uint4*)o)[i] = out;
}

// ---------------------------------------------------------------- LayerNorm
__global__ __launch_bounds__(256) void ln_kernel(const void* __restrict__ x_,
                                                 const void* __restrict__ g_,
                                                 const void* __restrict__ b_,
                                                 u16* __restrict__ out,
                                                 const int* __restrict__ flagp) {
    int flag = *flagp;
    int row = blockIdx.x;
    int tid = threadIdx.x;
    float v[4];
    if (flag) {
        const u16* xr = (const u16*)x_ + (size_t)row * 1024;
        uint2 d = *(const uint2*)&xr[tid * 4];
        v[0] = bf2f((u16)(d.x & 0xffff));
        v[1] = bf2f((u16)(d.x >> 16));
        v[2] = bf2f((u16)(d.y & 0xffff));
        v[3] = bf2f((u16)(d.y >> 16));
    } else {
        const float* xr = (const float*)x_ + (size_t)row * 1024;
        float4 d = *(const float4*)&xr[tid * 4];
        v[0] = d.x; v[1] = d.y; v[2] = d.z; v[3] = d.w;
    }
    float s  = v[0] + v[1] + v[2] + v[3];
    float ss = v[0]*v[0] + v[1]*v[1] + v[2]*v[2] + v[3]*v[3];
    for (int off = 1; off < 64; off <<= 1) {
        s  += __shfl_xor(s,  off, 64);
        ss += __shfl_xor(ss, off, 64);
    }
    __shared__ float red[8];
    int wave = tid >> 6, lane = tid & 63;
    if (lane == 0) { red[wave] = s; red[4 + wave] = ss; }
    __syncthreads();
    s  = red[0] + red[1] + red[2] + red[3];
    ss = red[4] + red[5] + red[6] + red[7];
    float mu   = s * (1.0f / 1024.0f);
    float var  = ss * (1.0f / 1024.0f) - mu * mu;
    float rstd = rsqrtf(var + 1e-5f);
    u16 r01[4];
    for (int j = 0; j < 4; ++j) {
        float g, bb;
        if (flag) { g = bf2f(((const u16*)g_)[tid * 4 + j]); bb = bf2f(((const u16*)b_)[tid * 4 + j]); }
        else      { g = ((const float*)g_)[tid * 4 + j];     bb = ((const float*)b_)[tid * 4 + j]; }
        r01[j] = f2bf((v[j] - mu) * rstd * g + bb);
    }
    uint2 o;
    o.x = (u32)r01[0] | ((u32)r01[1] << 16);
    o.y = (u32)r01[2] | ((u32)r01[3] << 16);
    *(uint2*)&out[(size_t)row * 1024 + tid * 4] = o;
}

// ---------------------------------------------------------------- Transpose
__global__ __launch_bounds__(256) void transpose64(const void* __restrict__ src_,
                                                   u16* __restrict__ dst,
                                                   int rows, int cols,
                                                   const int* __restrict__ flagp) {
    __shared__ u16 t[64][65];
    int flag = *flagp;
    int bx = blockIdx.x * 64;
    int by = blockIdx.y * 64;
    int tid = threadIdx.x;
    for (int i = 0; i < 16; ++i) {
        int r = i * 4 + (tid >> 6);
        int c = tid & 63;
        size_t idx = (size_t)(by + r) * cols + bx + c;
        t[r][c] = flag ? ((const u16*)src_)[idx] : f2bf(((const float*)src_)[idx]);
    }
    __syncthreads();
    for (int i = 0; i < 16; ++i) {
        int r = i * 4 + (tid >> 6);
        int c = tid & 63;
        dst[(size_t)(bx + r) * rows + by + c] = t[c][r];
    }
}

// ------------------------------------------------------- GEMM 128x128 (B^T)
// 1-D grid, XCD-grouped: the 8 bn-siblings of each bm-row map to one XCD
// (hardware round-robins xcd = blockIdx.x % 8), so the shared A-tile (256 KB)
// and B (2 MB) stay in that XCD's L2. mdiv = (M/128)/8.
__global__ __launch_bounds__(256, 2) void gemm128(const u16* __restrict__ A,
                                                  const u16* __restrict__ Bt,
                                                  void* __restrict__ C_,
                                                  int M, int N, int K,
                                                  const int* __restrict__ flagp,
                                                  int c_flagged, float cscale,
                                                  int vt_mode, int mdiv) {
    __shared__ u16 As[128 * 64];
    __shared__ u16 Bs[128 * 64];
    int flag = *flagp;
    bool c_bf16 = c_flagged ? (flag != 0) : true;

    int id  = blockIdx.x;
    int j   = id >> 3;
    int gy  = (id & 7) + 8 * (j % mdiv);
    int bnt = j / mdiv;

    int tid  = threadIdx.x;
    int wave = tid >> 6, lane = tid & 63;
    int quad = lane >> 4, l16 = lane & 15;
    size_t bm = (size_t)gy * 128;
    size_t bn = (size_t)bnt * 128;
    int wm = (wave >> 1) * 64, wn = (wave & 1) * 64;

    int lr  = lane >> 3;
    int csw = (lane & 7) ^ lr;
    const u16* Ag = A  + (bm + wave * 32 + lr) * (size_t)K + csw * 8;
    const u16* Bg = Bt + (bn + wave * 32 + lr) * (size_t)K + csw * 8;
    u16* Al = &As[(wave * 32) * 64];
    u16* Bl = &Bs[(wave * 32) * 64];

    f32x4 acc[4][4];
#pragma unroll
    for (int i = 0; i < 4; ++i)
#pragma unroll
        for (int jj = 0; jj < 4; ++jj)
            acc[i][jj] = (f32x4){0.f, 0.f, 0.f, 0.f};

    int rsw = l16 & 7;

    for (int k0 = 0; k0 < K; k0 += 64) {
        __syncthreads();
#pragma unroll
        for (int i = 0; i < 4; ++i) {
            async16(Al + i * 8 * 64, Ag + (size_t)i * 8 * K + k0);
            async16(Bl + i * 8 * 64, Bg + (size_t)i * 8 * K + k0);
        }
        __syncthreads();

#pragma unroll
        for (int ks = 0; ks < 2; ++ks) {
            int chunk = ((ks << 2) | quad) ^ rsw;
            bf16x8 af[4], bfr[4];
#pragma unroll
            for (int mi = 0; mi < 4; ++mi)
                af[mi]  = *(const bf16x8*)&As[(wm + mi * 16 + l16) * 64 + chunk * 8];
#pragma unroll
            for (int ni = 0; ni < 4; ++ni)
                bfr[ni] = *(const bf16x8*)&Bs[(wn + ni * 16 + l16) * 64 + chunk * 8];
#pragma unroll
            for (int mi = 0; mi < 4; ++mi)
#pragma unroll
                for (int ni = 0; ni < 4; ++ni)
                    acc[mi][ni] = __builtin_amdgcn_mfma_f32_16x16x32_bf16(
                        af[mi], bfr[ni], acc[mi][ni], 0, 0, 0);
        }
    }

    if (vt_mode) {
        u16* C = (u16*)C_;
#pragma unroll
        for (int mi = 0; mi < 4; ++mi)
#pragma unroll
            for (int ni = 0; ni < 4; ++ni) {
                size_t m = bm + wm + mi * 16 + quad * 4;
                size_t n = bn + wn + ni * 16 + l16;
                size_t bb = m >> 11, kv = m & 2047;
                size_t hh = n >> 6,  d  = n & 63;
                u16 t4[4];
#pragma unroll
                for (int r = 0; r < 4; ++r) t4[r] = f2bf(acc[mi][ni][r]);
                *(uint2*)&C[((bb * 16 + hh) * 64 + d) * 2048 + kv] = *(const uint2*)t4;
            }
    } else {
#pragma unroll
        for (int mi = 0; mi < 4; ++mi)
#pragma unroll
            for (int ni = 0; ni < 4; ++ni)
#pragma unroll
                for (int r = 0; r < 4; ++r) {
                    size_t row = bm + wm + mi * 16 + quad * 4 + r;
                    size_t col = bn + wn + ni * 16 + l16;
                    float val = acc[mi][ni][r] * cscale;
                    if (c_bf16) ((u16*)C_)[row * N + col]   = f2bf(val);
                    else        ((float*)C_)[row * N + col] = val;
                }
    }
}

// ---------------------------------------------------------------- Attention
// S^T formulation + XCD-grouped blocks + async XOR-swizzled staging.
// Round 1: double-buffered K/V LDS, single raw barrier per tile (T3-min):
// stage tile t+1 into buf^1, compute tile t from buf, then vmcnt(0)+s_barrier.
// Load latency for t+1 hides under tile-t compute; only one barrier/tile.
__global__ __launch_bounds__(256) void attn_kernel(const u16* __restrict__ qg,
                                                   const u16* __restrict__ kg,
                                                   const u16* __restrict__ vtg,
                                                   const u8* __restrict__ masku,
                                                   u16* __restrict__ og) {
    __shared__ u16 Ks[2 * 64 * 64];
    __shared__ u16 Vst[2 * 64 * 64];     // [d][kv], swizzled

    const int NQc = 1024, NKVc = 2048, HD = 1024;
    int id = blockIdx.x;
    int j  = id >> 3;
    int qt = j >> 3;                       // [0,16)
    int g  = (id & 7) + ((j & 7) << 3);    // [0,64) (b,h) group; xcd = id&7
    int h  = g & 15;
    int b  = g >> 4;

    int tid  = threadIdx.x;
    int wave = tid >> 6, lane = tid & 63;
    int quad = lane >> 4, l16 = lane & 15;
    int q0 = qt * 64;

    // Q fragment (B-operand: n=q=l16, k=d=quad*8+j) straight from global
    const u16* qrow = qg + ((size_t)b * NQc + q0 + wave * 16 + l16) * HD + h * 64;
    bf16x8 aq0 = *(const bf16x8*)&qrow[quad * 8];
    bf16x8 aq1 = *(const bf16x8*)&qrow[32 + quad * 8];

    // staging source addressing (per lane): row lr in 8-row group, chunk swizzle
    int lr  = lane >> 3;                   // [0,8)
    int csw = (lane & 7) ^ lr;             // source 16B chunk for phys lane&7
    const u16* kbase = kg  + ((size_t)b * NKVc + wave * 8 + lr) * HD + h * 64 + csw * 8;
    const u16* vbase = vtg + (((size_t)b * 16 + h) * 64 + wave * 8 + lr) * (size_t)NKVc + csw * 8;

    f32x4 O[4], lacc;
#pragma unroll
    for (int dt = 0; dt < 4; ++dt) O[dt] = (f32x4){0.f, 0.f, 0.f, 0.f};
    lacc = (f32x4){0.f, 0.f, 0.f, 0.f};

    bf16x4 ones4;
#pragma unroll
    for (int jj = 0; jj < 4; ++jj) ones4[jj] = (short)0x3F80;

    const u8* mrow = masku + ((size_t)b * NQc + q0 + wave * 16 + l16) * (size_t)NKVc;

    int l7 = l16 & 7;

    // prologue: stage tile 0 into buffer 0
    {
        u16* kl = Ks  + (wave * 8) * 64;
        u16* vl = Vst + (wave * 8) * 64;
#pragma unroll
        for (int i = 0; i < 2; ++i) {
            async16(kl + i * 32 * 64, kbase + (size_t)(i * 32) * HD);
            async16(vl + i * 32 * 64, vbase + (size_t)(i * 32) * NKVc);
        }
    }
    asm volatile("s_waitcnt vmcnt(0)" ::: "memory");
    __builtin_amdgcn_s_barrier();

    int cur = 0;
    for (int kv0 = 0; kv0 < NKVc; kv0 += 64) {
        // stage tile t+1 into the other buffer (loads fly under compute)
        if (kv0 + 64 < NKVc) {
            u16* kl = Ks  + (cur ^ 1) * 4096 + (wave * 8) * 64;
            u16* vl = Vst + (cur ^ 1) * 4096 + (wave * 8) * 64;
#pragma unroll
            for (int i = 0; i < 2; ++i) {
                async16(kl + i * 32 * 64, kbase + ((size_t)kv0 + 64 + i * 32) * HD);
                async16(vl + i * 32 * 64, vbase + (size_t)(i * 32) * NKVc + kv0 + 64);
            }
        }

        const u16* Kb = Ks  + cur * 4096;
        const u16* Vb = Vst + cur * 4096;

        // per nt: S^T tile -> exp2 -> mask -> bf16x4 P^T fragment
        bf16x4 pfr[4];
#pragma unroll
        for (int nt = 0; nt < 4; ++nt) {
            const u16* krow = Kb + (nt * 16 + l16) * 64;
            bf16x8 bk0 = *(const bf16x8*)&krow[(quad ^ l7) * 8];
            bf16x8 bk1 = *(const bf16x8*)&krow[((4 + quad) ^ l7) * 8];
            f32x4 st = (f32x4){0.f, 0.f, 0.f, 0.f};
            st = __builtin_amdgcn_mfma_f32_16x16x32_bf16(bk0, aq0, st, 0, 0, 0);
            st = __builtin_amdgcn_mfma_f32_16x16x32_bf16(bk1, aq1, st, 0, 0, 0);

            u32 mword = *(const u32*)&mrow[kv0 + nt * 16 + quad * 4];
            u32 p01 = pkbf(exp2f(st[0]), exp2f(st[1])) &
                      __builtin_amdgcn_perm(0u, mword, 0x01010000u);
            u32 p23 = pkbf(exp2f(st[2]), exp2f(st[3])) &
                      __builtin_amdgcn_perm(0u, mword, 0x03030202u);
            uint2 pu; pu.x = p01; pu.y = p23;
            pfr[nt] = *(const bf16x4*)&pu;

            lacc = __builtin_amdgcn_mfma_f32_16x16x16bf16_1k(ones4, pfr[nt], lacc, 0, 0, 0);
        }

        // O^T += V^T . P^T   (A-frag: d-row = dt*16+l16, kv = kvs*16+quad*4)
#pragma unroll
        for (int dt = 0; dt < 4; ++dt) {
            const u16* vrow = Vb + (dt * 16 + l16) * 64;
#pragma unroll
            for (int kvs = 0; kvs < 4; ++kvs) {
                int gran = ((kvs << 1) | (quad >> 1)) ^ l7;   // 16B granule (2 per read-half)
                bf16x4 av = *(const bf16x4*)&vrow[gran * 8 + (quad & 1) * 4];
                O[dt] = __builtin_amdgcn_mfma_f32_16x16x16bf16_1k(av, pfr[kvs], O[dt], 0, 0, 0);
            }
        }

        // single drain + barrier per tile: t+1 loads have landed under compute;
        // all waves' reads of buf[cur] completed before their barrier arrival.
        asm volatile("s_waitcnt vmcnt(0)" ::: "memory");
        __builtin_amdgcn_s_barrier();
        cur ^= 1;
    }

    // epilogue: O^T lane holds q=l16, d=dt*16+quad*4+r -> 4 consecutive d
    float inv = 1.0f / lacc[0];
    u16* orow = og + ((size_t)b * NQc + q0 + wave * 16 + l16) * HD + h * 64;
#pragma unroll
    for (int dt = 0; dt < 4; ++dt) {
        u16 t4[4];
#pragma unroll
        for (int r = 0; r < 4; ++r) t4[r] = f2bf(O[dt][r] * inv);
        *(uint2*)&orow[dt * 16 + quad * 4] = *(const uint2*)t4;
    }
}

// ---------------------------------------------------------------- launch
extern "C" void kernel_launch(void* const* d_in, const int* in_sizes, int n_in,
                              void* d_out, int out_size, void* d_ws, size_t ws_size,
                              hipStream_t stream) {
    const void* x     = d_in[0];
    const void* key   = d_in[1];
    const void* value = d_in[2];
    const int*  mask  = (const int*)d_in[3];
    const void* Wq    = d_in[4];
    const void* Wk    = d_in[5];
    const void* Wv    = d_in[6];
    const void* Wo    = d_in[7];
    const void* gamma = d_in[8];
    const void* beta  = d_in[9];

    // ws layout (65 MB), time-multiplexed:
    //  @1  xn [8MB] -> mask_u8 after Q-GEMM
    //  @9  kb [16MB] -> q [8MB] @9 + ao [8MB] @17
    //  @25 vb [16MB] -> k [16MB]
    //  @41 vT [16MB]
    //  @57..65 Wqt/Wkt/Wvt/Wot [2MB each]
    char* ws = (char*)d_ws;
    int* flag = (int*)(ws);
    u16* xn  = (u16*)(ws + ( 1ull << 20));
    u8*  mu8 = (u8*) (ws + ( 1ull << 20));
    u16* q   = (u16*)(ws + ( 9ull << 20));
    u16* kb  = (u16*)(ws + ( 9ull << 20));
    u16* ao  = (u16*)(ws + (17ull << 20));
    u16* k   = (u16*)(ws + (25ull << 20));
    u16* vb  = (u16*)(ws + (25ull << 20));
    u16* vT  = (u16*)(ws + (41ull << 20));
    u16* Wqt = (u16*)(ws + (57ull << 20));
    u16* Wkt = (u16*)(ws + (59ull << 20));
    u16* Wvt = (u16*)(ws + (61ull << 20));
    u16* Wot = (u16*)(ws + (63ull << 20));

    const float QSCALE = 0.125f * 1.44269504f;   // d^-0.5 * log2(e) for exp2 softmax

    detect_dtype<<<1, 256, 0, stream>>>((const u32*)x, flag);

    ln_kernel<<<4096, 256, 0, stream>>>(x, gamma, beta, xn, flag);

    dim3 tg(16, 16);
    transpose64<<<tg, 256, 0, stream>>>(Wq, Wqt, 1024, 1024, flag);
    transpose64<<<tg, 256, 0, stream>>>(Wk, Wkt, 1024, 1024, flag);
    transpose64<<<tg, 256, 0, stream>>>(Wv, Wvt, 1024, 1024, flag);
    transpose64<<<tg, 256, 0, stream>>>(Wo, Wot, 1024, 1024, flag);

    conv_bf16<<<4096, 256, 0, stream>>>(key,   kb, flag);
    conv_bf16<<<4096, 256, 0, stream>>>(value, vb, flag);

    // 1-D XCD-grouped grids: M=8192 -> 512 blocks, mdiv=8; M=4096 -> 256, mdiv=4
    gemm128<<<512, 256, 0, stream>>>(vb, Wvt, vT, 8192, 1024, 1024, flag, 0, 1.0f, 1, 8);
    gemm128<<<512, 256, 0, stream>>>(kb, Wkt, k,  8192, 1024, 1024, flag, 0, 1.0f, 0, 8);
    gemm128<<<256, 256, 0, stream>>>(xn, Wqt, q,  4096, 1024, 1024, flag, 0, QSCALE, 0, 4);

    mask_pack<<<2048, 256, 0, stream>>>(mask, mu8);

    attn_kernel<<<1024, 256, 0, stream>>>(q, k, vT, mu8, ao);

    gemm128<<<256, 256, 0, stream>>>(ao, Wot, d_out, 4096, 1024, 1024, flag, 1, 1.0f, 0, 4);
}

// Round 3
// 361.336 us; speedup vs baseline: 1.0985x; 1.0964x over previous
//
#include <hip/hip_runtime.h>

typedef unsigned short u16;
typedef unsigned int u32;
typedef unsigned char u8;

typedef __attribute__((ext_vector_type(8))) short bf16x8;
typedef __attribute__((ext_vector_type(4))) short bf16x4;
typedef __attribute__((ext_vector_type(4))) float f32x4;

__device__ __forceinline__ float bf2f(u16 u) {
    union { u32 i; float f; } v; v.i = ((u32)u) << 16; return v.f;
}
__device__ __forceinline__ u16 f2bf(float f) {
    union { float f; u32 i; } v; v.f = f;
    u32 r = v.i + 0x7fffu + ((v.i >> 16) & 1u);
    return (u16)(r >> 16);
}
// pack two f32 -> bf16x2 in one u32 (low = a, high = b) — software RNE (proven)
__device__ __forceinline__ u32 pkbf(float a, float b) {
    return (u32)f2bf(a) | ((u32)f2bf(b) << 16);
}
// raw v_exp_f32 (2^x). <=2 ULP vs OCML exp2f — negligible for softmax P.
__device__ __forceinline__ float fexp2(float x) { return __builtin_amdgcn_exp2f(x); }

// async global->LDS, 16B per lane; lds must be wave-uniform (lane*16 added by HW)
__device__ __forceinline__ void async16(u16* lds, const u16* g) {
    __builtin_amdgcn_global_load_lds(
        (const __attribute__((address_space(1))) void*)g,
        (__attribute__((address_space(3))) void*)lds, 16, 0, 0);
}

// ------------------------------------------------------------- dtype detect
__global__ __launch_bounds__(256) void detect_dtype(const u32* __restrict__ x,
                                                    int* __restrict__ flag) {
    int tid = threadIdx.x;
    int hits = 0;
    for (int i = 0; i < 4; ++i) {
        u32 w = x[tid * 4 + i];
        u32 e = (w >> 7) & 0xFFu;
        hits += (e >= 110u && e <= 131u) ? 1 : 0;
    }
    for (int off = 1; off < 64; off <<= 1) hits += __shfl_xor(hits, off, 64);
    __shared__ int red[4];
    int wave = tid >> 6, lane = tid & 63;
    if (lane == 0) red[wave] = hits;
    __syncthreads();
    if (tid == 0) flag[0] = (red[0] + red[1] + red[2] + red[3] > 512) ? 1 : 0;
}

// ------------------------------------------- convert pass (key+value fused)
__global__ __launch_bounds__(256) void conv_bf16_2(const void* __restrict__ src0,
                                                   const void* __restrict__ src1,
                                                   u16* __restrict__ dst0,
                                                   u16* __restrict__ dst1,
                                                   const int* __restrict__ flagp,
                                                   int half_blocks) {
    int flag = *flagp;
    const void* src = (blockIdx.x < (u32)half_blocks) ? src0 : src1;
    u16* dst = (blockIdx.x < (u32)half_blocks) ? dst0 : dst1;
    int blk = (blockIdx.x < (u32)half_blocks) ? blockIdx.x : (blockIdx.x - half_blocks);
    size_t i = (size_t)blk * 256 + threadIdx.x;
    if (flag) {
        ((uint4*)dst)[i] = ((const uint4*)src)[i];
    } else {
        const float4* s = (const float4*)src + i * 2;
        float4 f0 = s[0], f1 = s[1];
        u16 t[8];
        t[0] = f2bf(f0.x); t[1] = f2bf(f0.y); t[2] = f2bf(f0.z); t[3] = f2bf(f0.w);
        t[4] = f2bf(f1.x); t[5] = f2bf(f1.y); t[6] = f2bf(f1.z); t[7] = f2bf(f1.w);
        ((uint4*)dst)[i] = *(const uint4*)t;
    }
}

// ------------------------------------------------------------- mask pack
__global__ __launch_bounds__(256) void mask_pack(const int* __restrict__ m,
                                                 u8* __restrict__ o) {
    size_t i = (size_t)blockIdx.x * 256 + threadIdx.x;
    const int4* mp = (const int4*)m + i * 4;
    uint4 out;
    u32* op = (u32*)&out;
    for (int j = 0; j < 4; ++j) {
        int4 a = mp[j];
        op[j] = (a.x == 0 ? 0xFFu : 0u) | (a.y == 0 ? 0xFF00u : 0u) |
                (a.z == 0 ? 0xFF0000u : 0u) | (a.w == 0 ? 0xFF000000u : 0u);
    }
    ((uint4*)o)[i] = out;
}

// ---------------------------------------------------------------- LayerNorm
__global__ __launch_bounds__(256) void ln_kernel(const void* __restrict__ x_,
                                                 const void* __restrict__ g_,
                                                 const void* __restrict__ b_,
                                                 u16* __restrict__ out,
                                                 const int* __restrict__ flagp) {
    int flag = *flagp;
    int row = blockIdx.x;
    int tid = threadIdx.x;
    float v[4];
    if (flag) {
        const u16* xr = (const u16*)x_ + (size_t)row * 1024;
        uint2 d = *(const uint2*)&xr[tid * 4];
        v[0] = bf2f((u16)(d.x & 0xffff));
        v[1] = bf2f((u16)(d.x >> 16));
        v[2] = bf2f((u16)(d.y & 0xffff));
        v[3] = bf2f((u16)(d.y >> 16));
    } else {
        const float* xr = (const float*)x_ + (size_t)row * 1024;
        float4 d = *(const float4*)&xr[tid * 4];
        v[0] = d.x; v[1] = d.y; v[2] = d.z; v[3] = d.w;
    }
    float s  = v[0] + v[1] + v[2] + v[3];
    float ss = v[0]*v[0] + v[1]*v[1] + v[2]*v[2] + v[3]*v[3];
    for (int off = 1; off < 64; off <<= 1) {
        s  += __shfl_xor(s,  off, 64);
        ss += __shfl_xor(ss, off, 64);
    }
    __shared__ float red[8];
    int wave = tid >> 6, lane = tid & 63;
    if (lane == 0) { red[wave] = s; red[4 + wave] = ss; }
    __syncthreads();
    s  = red[0] + red[1] + red[2] + red[3];
    ss = red[4] + red[5] + red[6] + red[7];
    float mu   = s * (1.0f / 1024.0f);
    float var  = ss * (1.0f / 1024.0f) - mu * mu;
    float rstd = rsqrtf(var + 1e-5f);
    u16 r01[4];
    for (int j = 0; j < 4; ++j) {
        float g, bb;
        if (flag) { g = bf2f(((const u16*)g_)[tid * 4 + j]); bb = bf2f(((const u16*)b_)[tid * 4 + j]); }
        else      { g = ((const float*)g_)[tid * 4 + j];     bb = ((const float*)b_)[tid * 4 + j]; }
        r01[j] = f2bf((v[j] - mu) * rstd * g + bb);
    }
    uint2 o;
    o.x = (u32)r01[0] | ((u32)r01[1] << 16);
    o.y = (u32)r01[2] | ((u32)r01[3] << 16);
    *(uint2*)&out[(size_t)row * 1024 + tid * 4] = o;
}

// ------------------------------------------- Transpose (4 weights, 1 launch)
__global__ __launch_bounds__(256) void transpose64x4(const void* __restrict__ s0,
                                                     const void* __restrict__ s1,
                                                     const void* __restrict__ s2,
                                                     const void* __restrict__ s3,
                                                     u16* __restrict__ d0,
                                                     u16* __restrict__ d1,
                                                     u16* __restrict__ d2,
                                                     u16* __restrict__ d3,
                                                     int rows, int cols,
                                                     const int* __restrict__ flagp) {
    __shared__ u16 t[64][65];
    int flag = *flagp;
    const void* src_ = (blockIdx.z == 0) ? s0 : (blockIdx.z == 1) ? s1 :
                       (blockIdx.z == 2) ? s2 : s3;
    u16* dst = (blockIdx.z == 0) ? d0 : (blockIdx.z == 1) ? d1 :
               (blockIdx.z == 2) ? d2 : d3;
    int bx = blockIdx.x * 64;
    int by = blockIdx.y * 64;
    int tid = threadIdx.x;
    for (int i = 0; i < 16; ++i) {
        int r = i * 4 + (tid >> 6);
        int c = tid & 63;
        size_t idx = (size_t)(by + r) * cols + bx + c;
        t[r][c] = flag ? ((const u16*)src_)[idx] : f2bf(((const float*)src_)[idx]);
    }
    __syncthreads();
    for (int i = 0; i < 16; ++i) {
        int r = i * 4 + (tid >> 6);
        int c = tid & 63;
        dst[(size_t)(bx + r) * rows + by + c] = t[c][r];
    }
}

// ------------------------------------------------------- GEMM 128x128 (B^T)
// 1-D grid, XCD-grouped: the 8 bn-siblings of each bm-row map to one XCD
// (hardware round-robins xcd = blockIdx.x % 8), so the shared A-tile (256 KB)
// and B (2 MB) stay in that XCD's L2. mdiv = (M/128)/8.
__global__ __launch_bounds__(256, 2) void gemm128(const u16* __restrict__ A,
                                                  const u16* __restrict__ Bt,
                                                  void* __restrict__ C_,
                                                  int M, int N, int K,
                                                  const int* __restrict__ flagp,
                                                  int c_flagged, float cscale,
                                                  int vt_mode, int mdiv) {
    __shared__ u16 As[128 * 64];
    __shared__ u16 Bs[128 * 64];
    int flag = *flagp;
    bool c_bf16 = c_flagged ? (flag != 0) : true;

    int id  = blockIdx.x;
    int j   = id >> 3;
    int gy  = (id & 7) + 8 * (j % mdiv);
    int bnt = j / mdiv;

    int tid  = threadIdx.x;
    int wave = tid >> 6, lane = tid & 63;
    int quad = lane >> 4, l16 = lane & 15;
    size_t bm = (size_t)gy * 128;
    size_t bn = (size_t)bnt * 128;
    int wm = (wave >> 1) * 64, wn = (wave & 1) * 64;

    int lr  = lane >> 3;
    int csw = (lane & 7) ^ lr;
    const u16* Ag = A  + (bm + wave * 32 + lr) * (size_t)K + csw * 8;
    const u16* Bg = Bt + (bn + wave * 32 + lr) * (size_t)K + csw * 8;
    u16* Al = &As[(wave * 32) * 64];
    u16* Bl = &Bs[(wave * 32) * 64];

    f32x4 acc[4][4];
#pragma unroll
    for (int i = 0; i < 4; ++i)
#pragma unroll
        for (int jj = 0; jj < 4; ++jj)
            acc[i][jj] = (f32x4){0.f, 0.f, 0.f, 0.f};

    int rsw = l16 & 7;

    for (int k0 = 0; k0 < K; k0 += 64) {
        __syncthreads();
#pragma unroll
        for (int i = 0; i < 4; ++i) {
            async16(Al + i * 8 * 64, Ag + (size_t)i * 8 * K + k0);
            async16(Bl + i * 8 * 64, Bg + (size_t)i * 8 * K + k0);
        }
        __syncthreads();

#pragma unroll
        for (int ks = 0; ks < 2; ++ks) {
            int chunk = ((ks << 2) | quad) ^ rsw;
            bf16x8 af[4], bfr[4];
#pragma unroll
            for (int mi = 0; mi < 4; ++mi)
                af[mi]  = *(const bf16x8*)&As[(wm + mi * 16 + l16) * 64 + chunk * 8];
#pragma unroll
            for (int ni = 0; ni < 4; ++ni)
                bfr[ni] = *(const bf16x8*)&Bs[(wn + ni * 16 + l16) * 64 + chunk * 8];
#pragma unroll
            for (int mi = 0; mi < 4; ++mi)
#pragma unroll
                for (int ni = 0; ni < 4; ++ni)
                    acc[mi][ni] = __builtin_amdgcn_mfma_f32_16x16x32_bf16(
                        af[mi], bfr[ni], acc[mi][ni], 0, 0, 0);
        }
    }

    if (vt_mode) {
        u16* C = (u16*)C_;
#pragma unroll
        for (int mi = 0; mi < 4; ++mi)
#pragma unroll
            for (int ni = 0; ni < 4; ++ni) {
                size_t m = bm + wm + mi * 16 + quad * 4;
                size_t n = bn + wn + ni * 16 + l16;
                size_t bb = m >> 11, kv = m & 2047;
                size_t hh = n >> 6,  d  = n & 63;
                u16 t4[4];
#pragma unroll
                for (int r = 0; r < 4; ++r) t4[r] = f2bf(acc[mi][ni][r]);
                *(uint2*)&C[((bb * 16 + hh) * 64 + d) * 2048 + kv] = *(const uint2*)t4;
            }
    } else {
#pragma unroll
        for (int mi = 0; mi < 4; ++mi)
#pragma unroll
            for (int ni = 0; ni < 4; ++ni)
#pragma unroll
                for (int r = 0; r < 4; ++r) {
                    size_t row = bm + wm + mi * 16 + quad * 4 + r;
                    size_t col = bn + wn + ni * 16 + l16;
                    float val = acc[mi][ni][r] * cscale;
                    if (c_bf16) ((u16*)C_)[row * N + col]   = f2bf(val);
                    else        ((float*)C_)[row * N + col] = val;
                }
    }
}

// ---------------------------------------------------------------- Attention
// S^T formulation + XCD-grouped blocks + async XOR-swizzled staging.
// Round 2: single-buffer structure (round-0, proven 96us; dbuf regressed),
// exp2f -> raw v_exp_f32 via __builtin_amdgcn_exp2f (cuts OCML wrapper VALU).
__global__ __launch_bounds__(256) void attn_kernel(const u16* __restrict__ qg,
                                                   const u16* __restrict__ kg,
                                                   const u16* __restrict__ vtg,
                                                   const u8* __restrict__ masku,
                                                   u16* __restrict__ og) {
    __shared__ u16 Ks[64 * 64];
    __shared__ u16 Vst[64 * 64];     // [d][kv], swizzled

    const int NQc = 1024, NKVc = 2048, HD = 1024;
    int id = blockIdx.x;
    int j  = id >> 3;
    int qt = j >> 3;                       // [0,16)
    int g  = (id & 7) + ((j & 7) << 3);    // [0,64) (b,h) group; xcd = id&7
    int h  = g & 15;
    int b  = g >> 4;

    int tid  = threadIdx.x;
    int wave = tid >> 6, lane = tid & 63;
    int quad = lane >> 4, l16 = lane & 15;
    int q0 = qt * 64;

    // Q fragment (B-operand: n=q=l16, k=d=quad*8+j) straight from global
    const u16* qrow = qg + ((size_t)b * NQc + q0 + wave * 16 + l16) * HD + h * 64;
    bf16x8 aq0 = *(const bf16x8*)&qrow[quad * 8];
    bf16x8 aq1 = *(const bf16x8*)&qrow[32 + quad * 8];

    // staging source addressing (per lane): row lr in 8-row group, chunk swizzle
    int lr  = lane >> 3;                   // [0,8)
    int csw = (lane & 7) ^ lr;             // source 16B chunk for phys lane&7
    const u16* kbase = kg  + ((size_t)b * NKVc + wave * 8 + lr) * HD + h * 64 + csw * 8;
    const u16* vbase = vtg + (((size_t)b * 16 + h) * 64 + wave * 8 + lr) * (size_t)NKVc + csw * 8;
    u16* kl = Ks  + (wave * 8) * 64;
    u16* vl = Vst + (wave * 8) * 64;

    f32x4 O[4], lacc;
#pragma unroll
    for (int dt = 0; dt < 4; ++dt) O[dt] = (f32x4){0.f, 0.f, 0.f, 0.f};
    lacc = (f32x4){0.f, 0.f, 0.f, 0.f};

    bf16x4 ones4;
#pragma unroll
    for (int jj = 0; jj < 4; ++jj) ones4[jj] = (short)0x3F80;

    const u8* mrow = masku + ((size_t)b * NQc + q0 + wave * 16 + l16) * (size_t)NKVc;

    int l7 = l16 & 7;

    for (int kv0 = 0; kv0 < NKVc; kv0 += 64) {
        __syncthreads();
#pragma unroll
        for (int i = 0; i < 2; ++i) {
            // K rows kv0+i*32+wave*8+lr ; V (d-rows) i*32+wave*8+lr, cols kv0
            async16(kl + i * 32 * 64, kbase + ((size_t)kv0 + i * 32) * HD);
            async16(vl + i * 32 * 64, vbase + (size_t)(i * 32) * NKVc + kv0);
        }
        __syncthreads();

        // per nt: S^T tile -> exp2 -> mask -> bf16x4 P^T fragment
        bf16x4 pfr[4];
#pragma unroll
        for (int nt = 0; nt < 4; ++nt) {
            const u16* krow = Ks + (nt * 16 + l16) * 64;
            bf16x8 bk0 = *(const bf16x8*)&krow[(quad ^ l7) * 8];
            bf16x8 bk1 = *(const bf16x8*)&krow[((4 + quad) ^ l7) * 8];
            f32x4 st = (f32x4){0.f, 0.f, 0.f, 0.f};
            st = __builtin_amdgcn_mfma_f32_16x16x32_bf16(bk0, aq0, st, 0, 0, 0);
            st = __builtin_amdgcn_mfma_f32_16x16x32_bf16(bk1, aq1, st, 0, 0, 0);

            u32 mword = *(const u32*)&mrow[kv0 + nt * 16 + quad * 4];
            u32 p01 = pkbf(fexp2(st[0]), fexp2(st[1])) &
                      __builtin_amdgcn_perm(0u, mword, 0x01010000u);
            u32 p23 = pkbf(fexp2(st[2]), fexp2(st[3])) &
                      __builtin_amdgcn_perm(0u, mword, 0x03030202u);
            uint2 pu; pu.x = p01; pu.y = p23;
            pfr[nt] = *(const bf16x4*)&pu;

            lacc = __builtin_amdgcn_mfma_f32_16x16x16bf16_1k(ones4, pfr[nt], lacc, 0, 0, 0);
        }

        // O^T += V^T . P^T   (A-frag: d-row = dt*16+l16, kv = kvs*16+quad*4)
#pragma unroll
        for (int dt = 0; dt < 4; ++dt) {
            const u16* vrow = Vst + (dt * 16 + l16) * 64;
#pragma unroll
            for (int kvs = 0; kvs < 4; ++kvs) {
                int gran = ((kvs << 1) | (quad >> 1)) ^ l7;   // 16B granule (2 per read-half)
                bf16x4 av = *(const bf16x4*)&vrow[gran * 8 + (quad & 1) * 4];
                O[dt] = __builtin_amdgcn_mfma_f32_16x16x16bf16_1k(av, pfr[kvs], O[dt], 0, 0, 0);
            }
        }
    }

    // epilogue: O^T lane holds q=l16, d=dt*16+quad*4+r -> 4 consecutive d
    float inv = 1.0f / lacc[0];
    u16* orow = og + ((size_t)b * NQc + q0 + wave * 16 + l16) * HD + h * 64;
#pragma unroll
    for (int dt = 0; dt < 4; ++dt) {
        u16 t4[4];
#pragma unroll
        for (int r = 0; r < 4; ++r) t4[r] = f2bf(O[dt][r] * inv);
        *(uint2*)&orow[dt * 16 + quad * 4] = *(const uint2*)t4;
    }
}

// ---------------------------------------------------------------- launch
extern "C" void kernel_launch(void* const* d_in, const int* in_sizes, int n_in,
                              void* d_out, int out_size, void* d_ws, size_t ws_size,
                              hipStream_t stream) {
    const void* x     = d_in[0];
    const void* key   = d_in[1];
    const void* value = d_in[2];
    const int*  mask  = (const int*)d_in[3];
    const void* Wq    = d_in[4];
    const void* Wk    = d_in[5];
    const void* Wv    = d_in[6];
    const void* Wo    = d_in[7];
    const void* gamma = d_in[8];
    const void* beta  = d_in[9];

    // ws layout (65 MB), time-multiplexed:
    //  @1  xn [8MB] -> mask_u8 after Q-GEMM
    //  @9  kb [16MB] -> q [8MB] @9 + ao [8MB] @17
    //  @25 vb [16MB] -> k [16MB]
    //  @41 vT [16MB]
    //  @57..65 Wqt/Wkt/Wvt/Wot [2MB each]
    char* ws = (char*)d_ws;
    int* flag = (int*)(ws);
    u16* xn  = (u16*)(ws + ( 1ull << 20));
    u8*  mu8 = (u8*) (ws + ( 1ull << 20));
    u16* q   = (u16*)(ws + ( 9ull << 20));
    u16* kb  = (u16*)(ws + ( 9ull << 20));
    u16* ao  = (u16*)(ws + (17ull << 20));
    u16* k   = (u16*)(ws + (25ull << 20));
    u16* vb  = (u16*)(ws + (25ull << 20));
    u16* vT  = (u16*)(ws + (41ull << 20));
    u16* Wqt = (u16*)(ws + (57ull << 20));
    u16* Wkt = (u16*)(ws + (59ull << 20));
    u16* Wvt = (u16*)(ws + (61ull << 20));
    u16* Wot = (u16*)(ws + (63ull << 20));

    const float QSCALE = 0.125f * 1.44269504f;   // d^-0.5 * log2(e) for exp2 softmax

    detect_dtype<<<1, 256, 0, stream>>>((const u32*)x, flag);

    ln_kernel<<<4096, 256, 0, stream>>>(x, gamma, beta, xn, flag);

    dim3 tg4(16, 16, 4);
    transpose64x4<<<tg4, 256, 0, stream>>>(Wq, Wk, Wv, Wo, Wqt, Wkt, Wvt, Wot,
                                           1024, 1024, flag);

    conv_bf16_2<<<8192, 256, 0, stream>>>(key, value, kb, vb, flag, 4096);

    // 1-D XCD-grouped grids: M=8192 -> 512 blocks, mdiv=8; M=4096 -> 256, mdiv=4
    gemm128<<<512, 256, 0, stream>>>(vb, Wvt, vT, 8192, 1024, 1024, flag, 0, 1.0f, 1, 8);
    gemm128<<<512, 256, 0, stream>>>(kb, Wkt, k,  8192, 1024, 1024, flag, 0, 1.0f, 0, 8);
    gemm128<<<256, 256, 0, stream>>>(xn, Wqt, q,  4096, 1024, 1024, flag, 0, QSCALE, 0, 4);

    mask_pack<<<2048, 256, 0, stream>>>(mask, mu8);

    attn_kernel<<<1024, 256, 0, stream>>>(q, k, vT, mu8, ao);

    gemm128<<<256, 256, 0, stream>>>(ao, Wot, d_out, 4096, 1024, 1024, flag, 1, 1.0f, 0, 4);
}

// Round 4
// 352.490 us; speedup vs baseline: 1.1260x; 1.0251x over previous
//
#include <hip/hip_runtime.h>

typedef unsigned short u16;
typedef unsigned int u32;
typedef unsigned char u8;
typedef unsigned long long u64;

typedef __attribute__((ext_vector_type(8))) short bf16x8;
typedef __attribute__((ext_vector_type(4))) short bf16x4;
typedef __attribute__((ext_vector_type(4))) float f32x4;

__device__ __forceinline__ float bf2f(u16 u) {
    union { u32 i; float f; } v; v.i = ((u32)u) << 16; return v.f;
}
__device__ __forceinline__ u16 f2bf(float f) {
    union { float f; u32 i; } v; v.f = f;
    u32 r = v.i + 0x7fffu + ((v.i >> 16) & 1u);
    return (u16)(r >> 16);
}
// pack two f32 -> bf16x2 in one u32 (low = a, high = b) — software RNE (proven)
__device__ __forceinline__ u32 pkbf(float a, float b) {
    return (u32)f2bf(a) | ((u32)f2bf(b) << 16);
}
// raw v_exp_f32 (2^x). <=2 ULP vs OCML exp2f — negligible for softmax P.
__device__ __forceinline__ float fexp2(float x) { return __builtin_amdgcn_exp2f(x); }

// async global->LDS, 16B per lane; lds must be wave-uniform (lane*16 added by HW)
__device__ __forceinline__ void async16(u16* lds, const u16* g) {
    __builtin_amdgcn_global_load_lds(
        (const __attribute__((address_space(1))) void*)g,
        (__attribute__((address_space(3))) void*)lds, 16, 0, 0);
}

// ------------------------------------------------------------- dtype detect
__global__ __launch_bounds__(256) void detect_dtype(const u32* __restrict__ x,
                                                    int* __restrict__ flag) {
    int tid = threadIdx.x;
    int hits = 0;
    for (int i = 0; i < 4; ++i) {
        u32 w = x[tid * 4 + i];
        u32 e = (w >> 7) & 0xFFu;
        hits += (e >= 110u && e <= 131u) ? 1 : 0;
    }
    for (int off = 1; off < 64; off <<= 1) hits += __shfl_xor(hits, off, 64);
    __shared__ int red[4];
    int wave = tid >> 6, lane = tid & 63;
    if (lane == 0) red[wave] = hits;
    __syncthreads();
    if (tid == 0) flag[0] = (red[0] + red[1] + red[2] + red[3] > 512) ? 1 : 0;
}

// ------------------------------------------- convert pass (key+value fused)
__global__ __launch_bounds__(256) void conv_bf16_2(const void* __restrict__ src0,
                                                   const void* __restrict__ src1,
                                                   u16* __restrict__ dst0,
                                                   u16* __restrict__ dst1,
                                                   const int* __restrict__ flagp,
                                                   int half_blocks) {
    int flag = *flagp;
    const void* src = (blockIdx.x < (u32)half_blocks) ? src0 : src1;
    u16* dst = (blockIdx.x < (u32)half_blocks) ? dst0 : dst1;
    int blk = (blockIdx.x < (u32)half_blocks) ? blockIdx.x : (blockIdx.x - half_blocks);
    size_t i = (size_t)blk * 256 + threadIdx.x;
    if (flag) {
        ((uint4*)dst)[i] = ((const uint4*)src)[i];
    } else {
        const float4* s = (const float4*)src + i * 2;
        float4 f0 = s[0], f1 = s[1];
        u16 t[8];
        t[0] = f2bf(f0.x); t[1] = f2bf(f0.y); t[2] = f2bf(f0.z); t[3] = f2bf(f0.w);
        t[4] = f2bf(f1.x); t[5] = f2bf(f1.y); t[6] = f2bf(f1.z); t[7] = f2bf(f1.w);
        ((uint4*)dst)[i] = *(const uint4*)t;
    }
}

// ------------------------------------------------------------ mask -> bits
// keep-bit = (m == 0). __ballot bit l == lane l == kv (base+l), so each wave
// packs one q-row (2048 ints) into 32 u64 words, bit index == kv index.
__global__ __launch_bounds__(256) void mask_bits(const int* __restrict__ m,
                                                 u64* __restrict__ o) {
    int wid  = (blockIdx.x * 256 + threadIdx.x) >> 6;
    int lane = threadIdx.x & 63;
    size_t base = (size_t)wid * 2048;
    for (int it = 0; it < 8; ++it) {
        u64 b0 = __ballot(m[base + it * 256 +   0 + lane] == 0);
        u64 b1 = __ballot(m[base + it * 256 +  64 + lane] == 0);
        u64 b2 = __ballot(m[base + it * 256 + 128 + lane] == 0);
        u64 b3 = __ballot(m[base + it * 256 + 192 + lane] == 0);
        if (lane == 0) {
            size_t idx = (base + it * 256) >> 6;
            o[idx + 0] = b0; o[idx + 1] = b1; o[idx + 2] = b2; o[idx + 3] = b3;
        }
    }
}

// ---------------------------------------------------------------- LayerNorm
__global__ __launch_bounds__(256) void ln_kernel(const void* __restrict__ x_,
                                                 const void* __restrict__ g_,
                                                 const void* __restrict__ b_,
                                                 u16* __restrict__ out,
                                                 const int* __restrict__ flagp) {
    int flag = *flagp;
    int row = blockIdx.x;
    int tid = threadIdx.x;
    float v[4];
    if (flag) {
        const u16* xr = (const u16*)x_ + (size_t)row * 1024;
        uint2 d = *(const uint2*)&xr[tid * 4];
        v[0] = bf2f((u16)(d.x & 0xffff));
        v[1] = bf2f((u16)(d.x >> 16));
        v[2] = bf2f((u16)(d.y & 0xffff));
        v[3] = bf2f((u16)(d.y >> 16));
    } else {
        const float* xr = (const float*)x_ + (size_t)row * 1024;
        float4 d = *(const float4*)&xr[tid * 4];
        v[0] = d.x; v[1] = d.y; v[2] = d.z; v[3] = d.w;
    }
    float s  = v[0] + v[1] + v[2] + v[3];
    float ss = v[0]*v[0] + v[1]*v[1] + v[2]*v[2] + v[3]*v[3];
    for (int off = 1; off < 64; off <<= 1) {
        s  += __shfl_xor(s,  off, 64);
        ss += __shfl_xor(ss, off, 64);
    }
    __shared__ float red[8];
    int wave = tid >> 6, lane = tid & 63;
    if (lane == 0) { red[wave] = s; red[4 + wave] = ss; }
    __syncthreads();
    s  = red[0] + red[1] + red[2] + red[3];
    ss = red[4] + red[5] + red[6] + red[7];
    float mu   = s * (1.0f / 1024.0f);
    float var  = ss * (1.0f / 1024.0f) - mu * mu;
    float rstd = rsqrtf(var + 1e-5f);
    u16 r01[4];
    for (int j = 0; j < 4; ++j) {
        float g, bb;
        if (flag) { g = bf2f(((const u16*)g_)[tid * 4 + j]); bb = bf2f(((const u16*)b_)[tid * 4 + j]); }
        else      { g = ((const float*)g_)[tid * 4 + j];     bb = ((const float*)b_)[tid * 4 + j]; }
        r01[j] = f2bf((v[j] - mu) * rstd * g + bb);
    }
    uint2 o;
    o.x = (u32)r01[0] | ((u32)r01[1] << 16);
    o.y = (u32)r01[2] | ((u32)r01[3] << 16);
    *(uint2*)&out[(size_t)row * 1024 + tid * 4] = o;
}

// ------------------------------------------- Transpose (4 weights, 1 launch)
__global__ __launch_bounds__(256) void transpose64x4(const void* __restrict__ s0,
                                                     const void* __restrict__ s1,
                                                     const void* __restrict__ s2,
                                                     const void* __restrict__ s3,
                                                     u16* __restrict__ d0,
                                                     u16* __restrict__ d1,
                                                     u16* __restrict__ d2,
                                                     u16* __restrict__ d3,
                                                     int rows, int cols,
                                                     const int* __restrict__ flagp) {
    __shared__ u16 t[64][65];
    int flag = *flagp;
    const void* src_ = (blockIdx.z == 0) ? s0 : (blockIdx.z == 1) ? s1 :
                       (blockIdx.z == 2) ? s2 : s3;
    u16* dst = (blockIdx.z == 0) ? d0 : (blockIdx.z == 1) ? d1 :
               (blockIdx.z == 2) ? d2 : d3;
    int bx = blockIdx.x * 64;
    int by = blockIdx.y * 64;
    int tid = threadIdx.x;
    for (int i = 0; i < 16; ++i) {
        int r = i * 4 + (tid >> 6);
        int c = tid & 63;
        size_t idx = (size_t)(by + r) * cols + bx + c;
        t[r][c] = flag ? ((const u16*)src_)[idx] : f2bf(((const float*)src_)[idx]);
    }
    __syncthreads();
    for (int i = 0; i < 16; ++i) {
        int r = i * 4 + (tid >> 6);
        int c = tid & 63;
        dst[(size_t)(bx + r) * rows + by + c] = t[c][r];
    }
}

// ------------------------------------------------------- GEMM 128x128 (B^T)
__global__ __launch_bounds__(256, 2) void gemm128(const u16* __restrict__ A,
                                                  const u16* __restrict__ Bt,
                                                  void* __restrict__ C_,
                                                  int M, int N, int K,
                                                  const int* __restrict__ flagp,
                                                  int c_flagged, float cscale,
                                                  int vt_mode, int mdiv) {
    __shared__ u16 As[128 * 64];
    __shared__ u16 Bs[128 * 64];
    int flag = *flagp;
    bool c_bf16 = c_flagged ? (flag != 0) : true;

    int id  = blockIdx.x;
    int j   = id >> 3;
    int gy  = (id & 7) + 8 * (j % mdiv);
    int bnt = j / mdiv;

    int tid  = threadIdx.x;
    int wave = tid >> 6, lane = tid & 63;
    int quad = lane >> 4, l16 = lane & 15;
    size_t bm = (size_t)gy * 128;
    size_t bn = (size_t)bnt * 128;
    int wm = (wave >> 1) * 64, wn = (wave & 1) * 64;

    int lr  = lane >> 3;
    int csw = (lane & 7) ^ lr;
    const u16* Ag = A  + (bm + wave * 32 + lr) * (size_t)K + csw * 8;
    const u16* Bg = Bt + (bn + wave * 32 + lr) * (size_t)K + csw * 8;
    u16* Al = &As[(wave * 32) * 64];
    u16* Bl = &Bs[(wave * 32) * 64];

    f32x4 acc[4][4];
#pragma unroll
    for (int i = 0; i < 4; ++i)
#pragma unroll
        for (int jj = 0; jj < 4; ++jj)
            acc[i][jj] = (f32x4){0.f, 0.f, 0.f, 0.f};

    int rsw = l16 & 7;

    for (int k0 = 0; k0 < K; k0 += 64) {
        __syncthreads();
#pragma unroll
        for (int i = 0; i < 4; ++i) {
            async16(Al + i * 8 * 64, Ag + (size_t)i * 8 * K + k0);
            async16(Bl + i * 8 * 64, Bg + (size_t)i * 8 * K + k0);
        }
        __syncthreads();

#pragma unroll
        for (int ks = 0; ks < 2; ++ks) {
            int chunk = ((ks << 2) | quad) ^ rsw;
            bf16x8 af[4], bfr[4];
#pragma unroll
            for (int mi = 0; mi < 4; ++mi)
                af[mi]  = *(const bf16x8*)&As[(wm + mi * 16 + l16) * 64 + chunk * 8];
#pragma unroll
            for (int ni = 0; ni < 4; ++ni)
                bfr[ni] = *(const bf16x8*)&Bs[(wn + ni * 16 + l16) * 64 + chunk * 8];
#pragma unroll
            for (int mi = 0; mi < 4; ++mi)
#pragma unroll
                for (int ni = 0; ni < 4; ++ni)
                    acc[mi][ni] = __builtin_amdgcn_mfma_f32_16x16x32_bf16(
                        af[mi], bfr[ni], acc[mi][ni], 0, 0, 0);
        }
    }

    if (vt_mode) {
        u16* C = (u16*)C_;
#pragma unroll
        for (int mi = 0; mi < 4; ++mi)
#pragma unroll
            for (int ni = 0; ni < 4; ++ni) {
                size_t m = bm + wm + mi * 16 + quad * 4;
                size_t n = bn + wn + ni * 16 + l16;
                size_t bb = m >> 11, kv = m & 2047;
                size_t hh = n >> 6,  d  = n & 63;
                u16 t4[4];
#pragma unroll
                for (int r = 0; r < 4; ++r) t4[r] = f2bf(acc[mi][ni][r]);
                *(uint2*)&C[((bb * 16 + hh) * 64 + d) * 2048 + kv] = *(const uint2*)t4;
            }
    } else {
#pragma unroll
        for (int mi = 0; mi < 4; ++mi)
#pragma unroll
            for (int ni = 0; ni < 4; ++ni)
#pragma unroll
                for (int r = 0; r < 4; ++r) {
                    size_t row = bm + wm + mi * 16 + quad * 4 + r;
                    size_t col = bn + wn + ni * 16 + l16;
                    float val = acc[mi][ni][r] * cscale;
                    if (c_bf16) ((u16*)C_)[row * N + col]   = f2bf(val);
                    else        ((float*)C_)[row * N + col] = val;
                }
    }
}

// ---------------------------------------------------------------- Attention
// S^T formulation, XCD-grouped, async XOR-swizzled staging (round-0 proven
// single-buffer loop). Round 3: 2-way KV-split — exp2 softmax is additive, so
// each half emits un-normalized f32 partials (O_half, l_half); combine divides
// by l0+l1. Grid 2048 -> 8 blocks/CU -> 32 waves/CU (was 16). Mask is bit-packed.
__global__ __launch_bounds__(256) void attn_kernel(const u16* __restrict__ qg,
                                                   const u16* __restrict__ kg,
                                                   const u16* __restrict__ vtg,
                                                   const u32* __restrict__ mbits,
                                                   float* __restrict__ o0,
                                                   float* __restrict__ o1b0,
                                                   float* __restrict__ o1b1,
                                                   float* __restrict__ o1b2,
                                                   float* __restrict__ o1b3,
                                                   float* __restrict__ lacc0,
                                                   float* __restrict__ lacc1) {
    __shared__ u16 Ks[64 * 64];
    __shared__ u16 Vst[64 * 64];     // [d][kv], swizzled

    const int NQc = 1024, NKVc = 2048, HD = 1024;
    int id = blockIdx.x;
    int j  = id >> 3;
    int qt2 = j >> 3;                      // [0,32)
    int half = qt2 >> 4;                   // KV half
    int qt = qt2 & 15;                     // [0,16)
    int g  = (id & 7) + ((j & 7) << 3);    // [0,64) (b,h) group; xcd = id&7
    int h  = g & 15;
    int b  = g >> 4;

    int tid  = threadIdx.x;
    int wave = tid >> 6, lane = tid & 63;
    int quad = lane >> 4, l16 = lane & 15;
    int q0 = qt * 64;

    // Q fragment (B-operand: n=q=l16, k=d=quad*8+j) straight from global
    const u16* qrow = qg + ((size_t)b * NQc + q0 + wave * 16 + l16) * HD + h * 64;
    bf16x8 aq0 = *(const bf16x8*)&qrow[quad * 8];
    bf16x8 aq1 = *(const bf16x8*)&qrow[32 + quad * 8];

    // staging source addressing (per lane): row lr in 8-row group, chunk swizzle
    int lr  = lane >> 3;                   // [0,8)
    int csw = (lane & 7) ^ lr;             // source 16B chunk for phys lane&7
    const u16* kbase = kg  + ((size_t)b * NKVc + wave * 8 + lr) * HD + h * 64 + csw * 8;
    const u16* vbase = vtg + (((size_t)b * 16 + h) * 64 + wave * 8 + lr) * (size_t)NKVc + csw * 8;
    u16* kl = Ks  + (wave * 8) * 64;
    u16* vl = Vst + (wave * 8) * 64;

    f32x4 O[4], lacc;
#pragma unroll
    for (int dt = 0; dt < 4; ++dt) O[dt] = (f32x4){0.f, 0.f, 0.f, 0.f};
    lacc = (f32x4){0.f, 0.f, 0.f, 0.f};

    bf16x4 ones4;
#pragma unroll
    for (int jj = 0; jj < 4; ++jj) ones4[jj] = (short)0x3F80;

    // bit-mask row: 64 u32 per q-row, bit index == kv index
    const u32* mrowb = mbits + ((size_t)b * NQc + q0 + wave * 16 + l16) * 64;

    int l7 = l16 & 7;
    int kvbeg = half << 10;

    for (int kv0 = kvbeg; kv0 < kvbeg + 1024; kv0 += 64) {
        __syncthreads();
#pragma unroll
        for (int i = 0; i < 2; ++i) {
            // K rows kv0+i*32+wave*8+lr ; V (d-rows) i*32+wave*8+lr, cols kv0
            async16(kl + i * 32 * 64, kbase + ((size_t)kv0 + i * 32) * HD);
            async16(vl + i * 32 * 64, vbase + (size_t)(i * 32) * NKVc + kv0);
        }
        __syncthreads();

        uint2 bw = *(const uint2*)&mrowb[kv0 >> 5];   // bits kv0..kv0+63

        // per nt: S^T tile -> exp2 -> mask -> bf16x4 P^T fragment
        bf16x4 pfr[4];
#pragma unroll
        for (int nt = 0; nt < 4; ++nt) {
            const u16* krow = Ks + (nt * 16 + l16) * 64;
            bf16x8 bk0 = *(const bf16x8*)&krow[(quad ^ l7) * 8];
            bf16x8 bk1 = *(const bf16x8*)&krow[((4 + quad) ^ l7) * 8];
            f32x4 st = (f32x4){0.f, 0.f, 0.f, 0.f};
            st = __builtin_amdgcn_mfma_f32_16x16x32_bf16(bk0, aq0, st, 0, 0, 0);
            st = __builtin_amdgcn_mfma_f32_16x16x32_bf16(bk1, aq1, st, 0, 0, 0);

            u32 w  = (nt < 2) ? bw.x : bw.y;
            u32 m4 = (w >> (((nt & 1) << 4) + (quad << 2))) & 0xFu;
            u32 m01 = ((m4 & 1u) ? 0xFFFFu : 0u) | ((m4 & 2u) ? 0xFFFF0000u : 0u);
            u32 m23 = ((m4 & 4u) ? 0xFFFFu : 0u) | ((m4 & 8u) ? 0xFFFF0000u : 0u);
            u32 p01 = pkbf(fexp2(st[0]), fexp2(st[1])) & m01;
            u32 p23 = pkbf(fexp2(st[2]), fexp2(st[3])) & m23;
            uint2 pu; pu.x = p01; pu.y = p23;
            pfr[nt] = *(const bf16x4*)&pu;

            lacc = __builtin_amdgcn_mfma_f32_16x16x16bf16_1k(ones4, pfr[nt], lacc, 0, 0, 0);
        }

        // O^T += V^T . P^T   (A-frag: d-row = dt*16+l16, kv = kvs*16+quad*4)
#pragma unroll
        for (int dt = 0; dt < 4; ++dt) {
            const u16* vrow = Vst + (dt * 16 + l16) * 64;
#pragma unroll
            for (int kvs = 0; kvs < 4; ++kvs) {
                int gran = ((kvs << 1) | (quad >> 1)) ^ l7;   // 16B granule (2 per read-half)
                bf16x4 av = *(const bf16x4*)&vrow[gran * 8 + (quad & 1) * 4];
                O[dt] = __builtin_amdgcn_mfma_f32_16x16x16bf16_1k(av, pfr[kvs], O[dt], 0, 0, 0);
            }
        }
    }

    // epilogue: un-normalized f32 partials. o0 layout [b][q][hd]; o1 per-b [q][hd].
    int qi = q0 + wave * 16 + l16;
    float* opart = half ? (b == 0 ? o1b0 : b == 1 ? o1b1 : b == 2 ? o1b2 : o1b3) : o0;
    size_t rbase = half ? (size_t)qi : ((size_t)b * NQc + qi);
    float* orow = opart + rbase * 1024 + h * 64;
#pragma unroll
    for (int dt = 0; dt < 4; ++dt)
        *(float4*)&orow[dt * 16 + quad * 4] = (float4){O[dt][0], O[dt][1], O[dt][2], O[dt][3]};

    float* lp = half ? lacc1 : lacc0;
    if (quad == 0) lp[((size_t)b * 16 + h) * 1024 + qi] = lacc[0];
}

// ------------------------------------------------------------- combine halves
__global__ __launch_bounds__(256) void combine_halves(const float* __restrict__ p0,
                                                      const float* __restrict__ p1b0,
                                                      const float* __restrict__ p1b1,
                                                      const float* __restrict__ p1b2,
                                                      const float* __restrict__ p1b3,
                                                      const float* __restrict__ l0,
                                                      const float* __restrict__ l1,
                                                      u16* __restrict__ ao) {
    int row = blockIdx.x;                 // b*1024 + q
    int b = row >> 10, qq = row & 1023;
    const float* p1 = (b == 0) ? p1b0 : (b == 1) ? p1b1 : (b == 2) ? p1b2 : p1b3;
    int tid = threadIdx.x;
    int hd = tid * 4;
    int h  = hd >> 6;
    float4 a = *(const float4*)&p0[(size_t)row * 1024 + hd];
    float4 c = *(const float4*)&p1[(size_t)qq  * 1024 + hd];
    size_t li = ((size_t)b * 16 + h) * 1024 + qq;
    float inv = 1.0f / (l0[li] + l1[li]);
    uint2 o;
    o.x = (u32)f2bf((a.x + c.x) * inv) | ((u32)f2bf((a.y + c.y) * inv) << 16);
    o.y = (u32)f2bf((a.z + c.z) * inv) | ((u32)f2bf((a.w + c.w) * inv) << 16);
    *(uint2*)&ao[(size_t)row * 1024 + hd] = o;
}

// ---------------------------------------------------------------- launch
extern "C" void kernel_launch(void* const* d_in, const int* in_sizes, int n_in,
                              void* d_out, int out_size, void* d_ws, size_t ws_size,
                              hipStream_t stream) {
    const void* x     = d_in[0];
    const void* key   = d_in[1];
    const void* value = d_in[2];
    const int*  mask  = (const int*)d_in[3];
    const void* Wq    = d_in[4];
    const void* Wk    = d_in[5];
    const void* Wv    = d_in[6];
    const void* Wo    = d_in[7];
    const void* gamma = d_in[8];
    const void* beta  = d_in[9];

    // ws layout (65 MB), time-multiplexed:
    //  @0   flag
    //  @1   xn [8MB, ..9]          -> after Q-gemm: mbits @1..2 ; Opart1_b0 @2..6 ;
    //                                 lacc0 @6..6.25 ; lacc1 @6.25..6.5
    //  @9   kb [16MB, ..25]        -> q [8MB] @9..17 ; @17..25: Opart1_b1/b2 ;
    //                                 after attn: ao [8MB] @9..17
    //  @25  vb [16MB, ..41]        -> k [16MB] @25..41
    //  @41  vT [16MB, ..57]
    //  @57  Wqt,Wkt,Wvt,Wot [2MB each] -> Wqt/Wkt region @57..61: Opart1_b3
    //  Opart0 = d_out (16MB f32, dead until final gemm)
    char* ws = (char*)d_ws;
    int* flag = (int*)(ws);
    u16* xn   = (u16*)(ws + ( 1ull << 20));
    u32* mbits= (u32*)(ws + ( 1ull << 20));
    float* o1b0 = (float*)(ws + ( 2ull << 20));
    float* la0  = (float*)(ws + ( 6ull << 20));
    float* la1  = (float*)(ws + ( 6ull << 20) + (256ull << 10));
    u16* q    = (u16*)(ws + ( 9ull << 20));
    u16* kb   = (u16*)(ws + ( 9ull << 20));
    u16* ao   = (u16*)(ws + ( 9ull << 20));
    float* o1b1 = (float*)(ws + (17ull << 20));
    float* o1b2 = (float*)(ws + (21ull << 20));
    u16* k    = (u16*)(ws + (25ull << 20));
    u16* vb   = (u16*)(ws + (25ull << 20));
    u16* vT   = (u16*)(ws + (41ull << 20));
    u16* Wqt  = (u16*)(ws + (57ull << 20));
    float* o1b3 = (float*)(ws + (57ull << 20));
    u16* Wkt  = (u16*)(ws + (59ull << 20));
    u16* Wvt  = (u16*)(ws + (61ull << 20));
    u16* Wot  = (u16*)(ws + (63ull << 20));
    float* o0 = (float*)d_out;

    const float QSCALE = 0.125f * 1.44269504f;   // d^-0.5 * log2(e) for exp2 softmax

    detect_dtype<<<1, 256, 0, stream>>>((const u32*)x, flag);

    ln_kernel<<<4096, 256, 0, stream>>>(x, gamma, beta, xn, flag);

    dim3 tg4(16, 16, 4);
    transpose64x4<<<tg4, 256, 0, stream>>>(Wq, Wk, Wv, Wo, Wqt, Wkt, Wvt, Wot,
                                           1024, 1024, flag);

    conv_bf16_2<<<8192, 256, 0, stream>>>(key, value, kb, vb, flag, 4096);

    // 1-D XCD-grouped grids: M=8192 -> 512 blocks, mdiv=8; M=4096 -> 256, mdiv=4
    gemm128<<<512, 256, 0, stream>>>(vb, Wvt, vT, 8192, 1024, 1024, flag, 0, 1.0f, 1, 8);
    gemm128<<<512, 256, 0, stream>>>(kb, Wkt, k,  8192, 1024, 1024, flag, 0, 1.0f, 0, 8);
    gemm128<<<256, 256, 0, stream>>>(xn, Wqt, q,  4096, 1024, 1024, flag, 0, QSCALE, 0, 4);

    // after Q-gemm (xn dead): pack mask into bits @1..2
    mask_bits<<<1024, 256, 0, stream>>>(mask, (u64*)mbits);

    attn_kernel<<<2048, 256, 0, stream>>>(q, k, vT, mbits,
                                          o0, o1b0, o1b1, o1b2, o1b3, la0, la1);

    combine_halves<<<4096, 256, 0, stream>>>(o0, o1b0, o1b1, o1b2, o1b3,
                                             la0, la1, ao);

    gemm128<<<256, 256, 0, stream>>>(ao, Wot, d_out, 4096, 1024, 1024, flag, 1, 1.0f, 0, 4);
}

// Round 5
// 350.043 us; speedup vs baseline: 1.1339x; 1.0070x over previous
//
#include <hip/hip_runtime.h>

typedef unsigned short u16;
typedef unsigned int u32;
typedef unsigned char u8;
typedef unsigned long long u64;

typedef __attribute__((ext_vector_type(8))) short bf16x8;
typedef __attribute__((ext_vector_type(4))) short bf16x4;
typedef __attribute__((ext_vector_type(4))) float f32x4;

__device__ __forceinline__ float bf2f(u16 u) {
    union { u32 i; float f; } v; v.i = ((u32)u) << 16; return v.f;
}
__device__ __forceinline__ u16 f2bf(float f) {
    union { float f; u32 i; } v; v.f = f;
    u32 r = v.i + 0x7fffu + ((v.i >> 16) & 1u);
    return (u16)(r >> 16);
}
// pack two f32 -> bf16x2 in one u32 (low = a, high = b) — software RNE (proven)
__device__ __forceinline__ u32 pkbf(float a, float b) {
    return (u32)f2bf(a) | ((u32)f2bf(b) << 16);
}
// raw v_exp_f32 (2^x). <=2 ULP vs OCML exp2f — negligible for softmax P.
__device__ __forceinline__ float fexp2(float x) { return __builtin_amdgcn_exp2f(x); }

// async global->LDS, 16B per lane; lds must be wave-uniform (lane*16 added by HW)
__device__ __forceinline__ void async16(u16* lds, const u16* g) {
    __builtin_amdgcn_global_load_lds(
        (const __attribute__((address_space(1))) void*)g,
        (__attribute__((address_space(3))) void*)lds, 16, 0, 0);
}

// ------------------------------------------------------------- dtype detect
__global__ __launch_bounds__(256) void detect_dtype(const u32* __restrict__ x,
                                                    int* __restrict__ flag) {
    int tid = threadIdx.x;
    int hits = 0;
    for (int i = 0; i < 4; ++i) {
        u32 w = x[tid * 4 + i];
        u32 e = (w >> 7) & 0xFFu;
        hits += (e >= 110u && e <= 131u) ? 1 : 0;
    }
    for (int off = 1; off < 64; off <<= 1) hits += __shfl_xor(hits, off, 64);
    __shared__ int red[4];
    int wave = tid >> 6, lane = tid & 63;
    if (lane == 0) red[wave] = hits;
    __syncthreads();
    if (tid == 0) flag[0] = (red[0] + red[1] + red[2] + red[3] > 512) ? 1 : 0;
}

// ------------------------------------------- convert pass (key+value fused)
__global__ __launch_bounds__(256) void conv_bf16_2(const void* __restrict__ src0,
                                                   const void* __restrict__ src1,
                                                   u16* __restrict__ dst0,
                                                   u16* __restrict__ dst1,
                                                   const int* __restrict__ flagp,
                                                   int half_blocks) {
    int flag = *flagp;
    const void* src = (blockIdx.x < (u32)half_blocks) ? src0 : src1;
    u16* dst = (blockIdx.x < (u32)half_blocks) ? dst0 : dst1;
    int blk = (blockIdx.x < (u32)half_blocks) ? blockIdx.x : (blockIdx.x - half_blocks);
    size_t i = (size_t)blk * 256 + threadIdx.x;
    if (flag) {
        ((uint4*)dst)[i] = ((const uint4*)src)[i];
    } else {
        const float4* s = (const float4*)src + i * 2;
        float4 f0 = s[0], f1 = s[1];
        u16 t[8];
        t[0] = f2bf(f0.x); t[1] = f2bf(f0.y); t[2] = f2bf(f0.z); t[3] = f2bf(f0.w);
        t[4] = f2bf(f1.x); t[5] = f2bf(f1.y); t[6] = f2bf(f1.z); t[7] = f2bf(f1.w);
        ((uint4*)dst)[i] = *(const uint4*)t;
    }
}

// ------------------------------------------------------------ mask -> bits
// keep-bit = (m == 0). __ballot bit l == lane l == kv (base+l), so each wave
// packs one q-row (2048 ints) into 32 u64 words, bit index == kv index.
__global__ __launch_bounds__(256) void mask_bits(const int* __restrict__ m,
                                                 u64* __restrict__ o) {
    int wid  = (blockIdx.x * 256 + threadIdx.x) >> 6;
    int lane = threadIdx.x & 63;
    size_t base = (size_t)wid * 2048;
    for (int it = 0; it < 8; ++it) {
        u64 b0 = __ballot(m[base + it * 256 +   0 + lane] == 0);
        u64 b1 = __ballot(m[base + it * 256 +  64 + lane] == 0);
        u64 b2 = __ballot(m[base + it * 256 + 128 + lane] == 0);
        u64 b3 = __ballot(m[base + it * 256 + 192 + lane] == 0);
        if (lane == 0) {
            size_t idx = (base + it * 256) >> 6;
            o[idx + 0] = b0; o[idx + 1] = b1; o[idx + 2] = b2; o[idx + 3] = b3;
        }
    }
}

// ---------------------------------------------------------------- LayerNorm
__global__ __launch_bounds__(256) void ln_kernel(const void* __restrict__ x_,
                                                 const void* __restrict__ g_,
                                                 const void* __restrict__ b_,
                                                 u16* __restrict__ out,
                                                 const int* __restrict__ flagp) {
    int flag = *flagp;
    int row = blockIdx.x;
    int tid = threadIdx.x;
    float v[4];
    if (flag) {
        const u16* xr = (const u16*)x_ + (size_t)row * 1024;
        uint2 d = *(const uint2*)&xr[tid * 4];
        v[0] = bf2f((u16)(d.x & 0xffff));
        v[1] = bf2f((u16)(d.x >> 16));
        v[2] = bf2f((u16)(d.y & 0xffff));
        v[3] = bf2f((u16)(d.y >> 16));
    } else {
        const float* xr = (const float*)x_ + (size_t)row * 1024;
        float4 d = *(const float4*)&xr[tid * 4];
        v[0] = d.x; v[1] = d.y; v[2] = d.z; v[3] = d.w;
    }
    float s  = v[0] + v[1] + v[2] + v[3];
    float ss = v[0]*v[0] + v[1]*v[1] + v[2]*v[2] + v[3]*v[3];
    for (int off = 1; off < 64; off <<= 1) {
        s  += __shfl_xor(s,  off, 64);
        ss += __shfl_xor(ss, off, 64);
    }
    __shared__ float red[8];
    int wave = tid >> 6, lane = tid & 63;
    if (lane == 0) { red[wave] = s; red[4 + wave] = ss; }
    __syncthreads();
    s  = red[0] + red[1] + red[2] + red[3];
    ss = red[4] + red[5] + red[6] + red[7];
    float mu   = s * (1.0f / 1024.0f);
    float var  = ss * (1.0f / 1024.0f) - mu * mu;
    float rstd = rsqrtf(var + 1e-5f);
    u16 r01[4];
    for (int j = 0; j < 4; ++j) {
        float g, bb;
        if (flag) { g = bf2f(((const u16*)g_)[tid * 4 + j]); bb = bf2f(((const u16*)b_)[tid * 4 + j]); }
        else      { g = ((const float*)g_)[tid * 4 + j];     bb = ((const float*)b_)[tid * 4 + j]; }
        r01[j] = f2bf((v[j] - mu) * rstd * g + bb);
    }
    uint2 o;
    o.x = (u32)r01[0] | ((u32)r01[1] << 16);
    o.y = (u32)r01[2] | ((u32)r01[3] << 16);
    *(uint2*)&out[(size_t)row * 1024 + tid * 4] = o;
}

// ------------------------------------------- Transpose (4 weights, 1 launch)
__global__ __launch_bounds__(256) void transpose64x4(const void* __restrict__ s0,
                                                     const void* __restrict__ s1,
                                                     const void* __restrict__ s2,
                                                     const void* __restrict__ s3,
                                                     u16* __restrict__ d0,
                                                     u16* __restrict__ d1,
                                                     u16* __restrict__ d2,
                                                     u16* __restrict__ d3,
                                                     int rows, int cols,
                                                     const int* __restrict__ flagp) {
    __shared__ u16 t[64][65];
    int flag = *flagp;
    const void* src_ = (blockIdx.z == 0) ? s0 : (blockIdx.z == 1) ? s1 :
                       (blockIdx.z == 2) ? s2 : s3;
    u16* dst = (blockIdx.z == 0) ? d0 : (blockIdx.z == 1) ? d1 :
               (blockIdx.z == 2) ? d2 : d3;
    int bx = blockIdx.x * 64;
    int by = blockIdx.y * 64;
    int tid = threadIdx.x;
    for (int i = 0; i < 16; ++i) {
        int r = i * 4 + (tid >> 6);
        int c = tid & 63;
        size_t idx = (size_t)(by + r) * cols + bx + c;
        t[r][c] = flag ? ((const u16*)src_)[idx] : f2bf(((const float*)src_)[idx]);
    }
    __syncthreads();
    for (int i = 0; i < 16; ++i) {
        int r = i * 4 + (tid >> 6);
        int c = tid & 63;
        dst[(size_t)(bx + r) * rows + by + c] = t[c][r];
    }
}

// ------------------------------------------------------- GEMM 128x128 (B^T)
__global__ __launch_bounds__(256, 2) void gemm128(const u16* __restrict__ A,
                                                  const u16* __restrict__ Bt,
                                                  void* __restrict__ C_,
                                                  int M, int N, int K,
                                                  const int* __restrict__ flagp,
                                                  int c_flagged, float cscale,
                                                  int vt_mode, int mdiv) {
    __shared__ u16 As[128 * 64];
    __shared__ u16 Bs[128 * 64];
    int flag = *flagp;
    bool c_bf16 = c_flagged ? (flag != 0) : true;

    int id  = blockIdx.x;
    int j   = id >> 3;
    int gy  = (id & 7) + 8 * (j % mdiv);
    int bnt = j / mdiv;

    int tid  = threadIdx.x;
    int wave = tid >> 6, lane = tid & 63;
    int quad = lane >> 4, l16 = lane & 15;
    size_t bm = (size_t)gy * 128;
    size_t bn = (size_t)bnt * 128;
    int wm = (wave >> 1) * 64, wn = (wave & 1) * 64;

    int lr  = lane >> 3;
    int csw = (lane & 7) ^ lr;
    const u16* Ag = A  + (bm + wave * 32 + lr) * (size_t)K + csw * 8;
    const u16* Bg = Bt + (bn + wave * 32 + lr) * (size_t)K + csw * 8;
    u16* Al = &As[(wave * 32) * 64];
    u16* Bl = &Bs[(wave * 32) * 64];

    f32x4 acc[4][4];
#pragma unroll
    for (int i = 0; i < 4; ++i)
#pragma unroll
        for (int jj = 0; jj < 4; ++jj)
            acc[i][jj] = (f32x4){0.f, 0.f, 0.f, 0.f};

    int rsw = l16 & 7;

    for (int k0 = 0; k0 < K; k0 += 64) {
        __syncthreads();
#pragma unroll
        for (int i = 0; i < 4; ++i) {
            async16(Al + i * 8 * 64, Ag + (size_t)i * 8 * K + k0);
            async16(Bl + i * 8 * 64, Bg + (size_t)i * 8 * K + k0);
        }
        __syncthreads();

#pragma unroll
        for (int ks = 0; ks < 2; ++ks) {
            int chunk = ((ks << 2) | quad) ^ rsw;
            bf16x8 af[4], bfr[4];
#pragma unroll
            for (int mi = 0; mi < 4; ++mi)
                af[mi]  = *(const bf16x8*)&As[(wm + mi * 16 + l16) * 64 + chunk * 8];
#pragma unroll
            for (int ni = 0; ni < 4; ++ni)
                bfr[ni] = *(const bf16x8*)&Bs[(wn + ni * 16 + l16) * 64 + chunk * 8];
#pragma unroll
            for (int mi = 0; mi < 4; ++mi)
#pragma unroll
                for (int ni = 0; ni < 4; ++ni)
                    acc[mi][ni] = __builtin_amdgcn_mfma_f32_16x16x32_bf16(
                        af[mi], bfr[ni], acc[mi][ni], 0, 0, 0);
        }
    }

    if (vt_mode) {
        u16* C = (u16*)C_;
#pragma unroll
        for (int mi = 0; mi < 4; ++mi)
#pragma unroll
            for (int ni = 0; ni < 4; ++ni) {
                size_t m = bm + wm + mi * 16 + quad * 4;
                size_t n = bn + wn + ni * 16 + l16;
                size_t bb = m >> 11, kv = m & 2047;
                size_t hh = n >> 6,  d  = n & 63;
                u16 t4[4];
#pragma unroll
                for (int r = 0; r < 4; ++r) t4[r] = f2bf(acc[mi][ni][r]);
                *(uint2*)&C[((bb * 16 + hh) * 64 + d) * 2048 + kv] = *(const uint2*)t4;
            }
    } else {
#pragma unroll
        for (int mi = 0; mi < 4; ++mi)
#pragma unroll
            for (int ni = 0; ni < 4; ++ni)
#pragma unroll
                for (int r = 0; r < 4; ++r) {
                    size_t row = bm + wm + mi * 16 + quad * 4 + r;
                    size_t col = bn + wn + ni * 16 + l16;
                    float val = acc[mi][ni][r] * cscale;
                    if (c_bf16) ((u16*)C_)[row * N + col]   = f2bf(val);
                    else        ((float*)C_)[row * N + col] = val;
                }
    }
}

// ----------------------------------- Merged V-GEMM + K-GEMM (one dispatch)
// Blocks 0..511: V-gemm (vb x Wvt -> vT, vt_mode epilogue).
// Blocks 512..1023: K-gemm (kb x Wkt -> k, plain bf16 epilogue).
// Both M=8192,N=1024,K=1024, mdiv=8. 512%8==0 so the XCD swizzle (id&7) is
// preserved per segment. 1024 blocks -> 4 blocks/CU (was 2 per dispatch).
__global__ __launch_bounds__(256, 2) void gemm128_vk(const u16* __restrict__ A0,
                                                     const u16* __restrict__ Bt0,
                                                     u16* __restrict__ C0,
                                                     const u16* __restrict__ A1,
                                                     const u16* __restrict__ Bt1,
                                                     u16* __restrict__ C1) {
    __shared__ u16 As[128 * 64];
    __shared__ u16 Bs[128 * 64];
    const int N = 1024, K = 1024, mdiv = 8;

    int id  = blockIdx.x;
    int seg = id >> 9;                 // 0 = V, 1 = K
    int lid = id & 511;
    const u16* A  = seg ? A1 : A0;
    const u16* Bt = seg ? Bt1 : Bt0;

    int j   = lid >> 3;
    int gy  = (lid & 7) + 8 * (j % mdiv);
    int bnt = j / mdiv;

    int tid  = threadIdx.x;
    int wave = tid >> 6, lane = tid & 63;
    int quad = lane >> 4, l16 = lane & 15;
    size_t bm = (size_t)gy * 128;
    size_t bn = (size_t)bnt * 128;
    int wm = (wave >> 1) * 64, wn = (wave & 1) * 64;

    int lr  = lane >> 3;
    int csw = (lane & 7) ^ lr;
    const u16* Ag = A  + (bm + wave * 32 + lr) * (size_t)K + csw * 8;
    const u16* Bg = Bt + (bn + wave * 32 + lr) * (size_t)K + csw * 8;
    u16* Al = &As[(wave * 32) * 64];
    u16* Bl = &Bs[(wave * 32) * 64];

    f32x4 acc[4][4];
#pragma unroll
    for (int i = 0; i < 4; ++i)
#pragma unroll
        for (int jj = 0; jj < 4; ++jj)
            acc[i][jj] = (f32x4){0.f, 0.f, 0.f, 0.f};

    int rsw = l16 & 7;

    for (int k0 = 0; k0 < K; k0 += 64) {
        __syncthreads();
#pragma unroll
        for (int i = 0; i < 4; ++i) {
            async16(Al + i * 8 * 64, Ag + (size_t)i * 8 * K + k0);
            async16(Bl + i * 8 * 64, Bg + (size_t)i * 8 * K + k0);
        }
        __syncthreads();

#pragma unroll
        for (int ks = 0; ks < 2; ++ks) {
            int chunk = ((ks << 2) | quad) ^ rsw;
            bf16x8 af[4], bfr[4];
#pragma unroll
            for (int mi = 0; mi < 4; ++mi)
                af[mi]  = *(const bf16x8*)&As[(wm + mi * 16 + l16) * 64 + chunk * 8];
#pragma unroll
            for (int ni = 0; ni < 4; ++ni)
                bfr[ni] = *(const bf16x8*)&Bs[(wn + ni * 16 + l16) * 64 + chunk * 8];
#pragma unroll
            for (int mi = 0; mi < 4; ++mi)
#pragma unroll
                for (int ni = 0; ni < 4; ++ni)
                    acc[mi][ni] = __builtin_amdgcn_mfma_f32_16x16x32_bf16(
                        af[mi], bfr[ni], acc[mi][ni], 0, 0, 0);
        }
    }

    if (!seg) {
        // V: transposed per-head layout [b][h][d][kv]
        u16* C = C0;
#pragma unroll
        for (int mi = 0; mi < 4; ++mi)
#pragma unroll
            for (int ni = 0; ni < 4; ++ni) {
                size_t m = bm + wm + mi * 16 + quad * 4;
                size_t n = bn + wn + ni * 16 + l16;
                size_t bb = m >> 11, kv = m & 2047;
                size_t hh = n >> 6,  d  = n & 63;
                u16 t4[4];
#pragma unroll
                for (int r = 0; r < 4; ++r) t4[r] = f2bf(acc[mi][ni][r]);
                *(uint2*)&C[((bb * 16 + hh) * 64 + d) * 2048 + kv] = *(const uint2*)t4;
            }
    } else {
        u16* C = C1;
#pragma unroll
        for (int mi = 0; mi < 4; ++mi)
#pragma unroll
            for (int ni = 0; ni < 4; ++ni)
#pragma unroll
                for (int r = 0; r < 4; ++r) {
                    size_t row = bm + wm + mi * 16 + quad * 4 + r;
                    size_t col = bn + wn + ni * 16 + l16;
                    C[row * N + col] = f2bf(acc[mi][ni][r]);
                }
    }
}

// ---------------------------------------------------------------- Attention
// S^T formulation, XCD-grouped, async XOR-swizzled staging, 2-way KV-split
// (exp2 softmax is additive: halves emit un-normalized f32 partials; combine
// divides by l0+l1). Grid 2048. Mask bit-packed.
__global__ __launch_bounds__(256) void attn_kernel(const u16* __restrict__ qg,
                                                   const u16* __restrict__ kg,
                                                   const u16* __restrict__ vtg,
                                                   const u32* __restrict__ mbits,
                                                   float* __restrict__ o0,
                                                   float* __restrict__ o1b0,
                                                   float* __restrict__ o1b1,
                                                   float* __restrict__ o1b2,
                                                   float* __restrict__ o1b3,
                                                   float* __restrict__ lacc0,
                                                   float* __restrict__ lacc1) {
    __shared__ u16 Ks[64 * 64];
    __shared__ u16 Vst[64 * 64];     // [d][kv], swizzled

    const int NQc = 1024, NKVc = 2048, HD = 1024;
    int id = blockIdx.x;
    int j  = id >> 3;
    int qt2 = j >> 3;                      // [0,32)
    int half = qt2 >> 4;                   // KV half
    int qt = qt2 & 15;                     // [0,16)
    int g  = (id & 7) + ((j & 7) << 3);    // [0,64) (b,h) group; xcd = id&7
    int h  = g & 15;
    int b  = g >> 4;

    int tid  = threadIdx.x;
    int wave = tid >> 6, lane = tid & 63;
    int quad = lane >> 4, l16 = lane & 15;
    int q0 = qt * 64;

    // Q fragment (B-operand: n=q=l16, k=d=quad*8+j) straight from global
    const u16* qrow = qg + ((size_t)b * NQc + q0 + wave * 16 + l16) * HD + h * 64;
    bf16x8 aq0 = *(const bf16x8*)&qrow[quad * 8];
    bf16x8 aq1 = *(const bf16x8*)&qrow[32 + quad * 8];

    // staging source addressing (per lane): row lr in 8-row group, chunk swizzle
    int lr  = lane >> 3;                   // [0,8)
    int csw = (lane & 7) ^ lr;             // source 16B chunk for phys lane&7
    const u16* kbase = kg  + ((size_t)b * NKVc + wave * 8 + lr) * HD + h * 64 + csw * 8;
    const u16* vbase = vtg + (((size_t)b * 16 + h) * 64 + wave * 8 + lr) * (size_t)NKVc + csw * 8;
    u16* kl = Ks  + (wave * 8) * 64;
    u16* vl = Vst + (wave * 8) * 64;

    f32x4 O[4], lacc;
#pragma unroll
    for (int dt = 0; dt < 4; ++dt) O[dt] = (f32x4){0.f, 0.f, 0.f, 0.f};
    lacc = (f32x4){0.f, 0.f, 0.f, 0.f};

    bf16x4 ones4;
#pragma unroll
    for (int jj = 0; jj < 4; ++jj) ones4[jj] = (short)0x3F80;

    // bit-mask row: 64 u32 per q-row, bit index == kv index
    const u32* mrowb = mbits + ((size_t)b * NQc + q0 + wave * 16 + l16) * 64;

    int l7 = l16 & 7;
    int kvbeg = half << 10;

    for (int kv0 = kvbeg; kv0 < kvbeg + 1024; kv0 += 64) {
        __syncthreads();
#pragma unroll
        for (int i = 0; i < 2; ++i) {
            // K rows kv0+i*32+wave*8+lr ; V (d-rows) i*32+wave*8+lr, cols kv0
            async16(kl + i * 32 * 64, kbase + ((size_t)kv0 + i * 32) * HD);
            async16(vl + i * 32 * 64, vbase + (size_t)(i * 32) * NKVc + kv0);
        }
        __syncthreads();

        uint2 bw = *(const uint2*)&mrowb[kv0 >> 5];   // bits kv0..kv0+63

        // per nt: S^T tile -> exp2 -> mask -> bf16x4 P^T fragment
        bf16x4 pfr[4];
#pragma unroll
        for (int nt = 0; nt < 4; ++nt) {
            const u16* krow = Ks + (nt * 16 + l16) * 64;
            bf16x8 bk0 = *(const bf16x8*)&krow[(quad ^ l7) * 8];
            bf16x8 bk1 = *(const bf16x8*)&krow[((4 + quad) ^ l7) * 8];
            f32x4 st = (f32x4){0.f, 0.f, 0.f, 0.f};
            st = __builtin_amdgcn_mfma_f32_16x16x32_bf16(bk0, aq0, st, 0, 0, 0);
            st = __builtin_amdgcn_mfma_f32_16x16x32_bf16(bk1, aq1, st, 0, 0, 0);

            u32 w  = (nt < 2) ? bw.x : bw.y;
            u32 m4 = (w >> (((nt & 1) << 4) + (quad << 2))) & 0xFu;
            u32 m01 = ((m4 & 1u) ? 0xFFFFu : 0u) | ((m4 & 2u) ? 0xFFFF0000u : 0u);
            u32 m23 = ((m4 & 4u) ? 0xFFFFu : 0u) | ((m4 & 8u) ? 0xFFFF0000u : 0u);
            u32 p01 = pkbf(fexp2(st[0]), fexp2(st[1])) & m01;
            u32 p23 = pkbf(fexp2(st[2]), fexp2(st[3])) & m23;
            uint2 pu; pu.x = p01; pu.y = p23;
            pfr[nt] = *(const bf16x4*)&pu;

            lacc = __builtin_amdgcn_mfma_f32_16x16x16bf16_1k(ones4, pfr[nt], lacc, 0, 0, 0);
        }

        // O^T += V^T . P^T   (A-frag: d-row = dt*16+l16, kv = kvs*16+quad*4)
#pragma unroll
        for (int dt = 0; dt < 4; ++dt) {
            const u16* vrow = Vst + (dt * 16 + l16) * 64;
#pragma unroll
            for (int kvs = 0; kvs < 4; ++kvs) {
                int gran = ((kvs << 1) | (quad >> 1)) ^ l7;   // 16B granule (2 per read-half)
                bf16x4 av = *(const bf16x4*)&vrow[gran * 8 + (quad & 1) * 4];
                O[dt] = __builtin_amdgcn_mfma_f32_16x16x16bf16_1k(av, pfr[kvs], O[dt], 0, 0, 0);
            }
        }
    }

    // epilogue: un-normalized f32 partials. o0 layout [b][q][hd]; o1 per-b [q][hd].
    int qi = q0 + wave * 16 + l16;
    float* opart = half ? (b == 0 ? o1b0 : b == 1 ? o1b1 : b == 2 ? o1b2 : o1b3) : o0;
    size_t rbase = half ? (size_t)qi : ((size_t)b * NQc + qi);
    float* orow = opart + rbase * 1024 + h * 64;
#pragma unroll
    for (int dt = 0; dt < 4; ++dt)
        *(float4*)&orow[dt * 16 + quad * 4] = (float4){O[dt][0], O[dt][1], O[dt][2], O[dt][3]};

    float* lp = half ? lacc1 : lacc0;
    if (quad == 0) lp[((size_t)b * 16 + h) * 1024 + qi] = lacc[0];
}

// ------------------------------------------------------------- combine halves
__global__ __launch_bounds__(256) void combine_halves(const float* __restrict__ p0,
                                                      const float* __restrict__ p1b0,
                                                      const float* __restrict__ p1b1,
                                                      const float* __restrict__ p1b2,
                                                      const float* __restrict__ p1b3,
                                                      const float* __restrict__ l0,
                                                      const float* __restrict__ l1,
                                                      u16* __restrict__ ao) {
    int row = blockIdx.x;                 // b*1024 + q
    int b = row >> 10, qq = row & 1023;
    const float* p1 = (b == 0) ? p1b0 : (b == 1) ? p1b1 : (b == 2) ? p1b2 : p1b3;
    int tid = threadIdx.x;
    int hd = tid * 4;
    int h  = hd >> 6;
    float4 a = *(const float4*)&p0[(size_t)row * 1024 + hd];
    float4 c = *(const float4*)&p1[(size_t)qq  * 1024 + hd];
    size_t li = ((size_t)b * 16 + h) * 1024 + qq;
    float inv = 1.0f / (l0[li] + l1[li]);
    uint2 o;
    o.x = (u32)f2bf((a.x + c.x) * inv) | ((u32)f2bf((a.y + c.y) * inv) << 16);
    o.y = (u32)f2bf((a.z + c.z) * inv) | ((u32)f2bf((a.w + c.w) * inv) << 16);
    *(uint2*)&ao[(size_t)row * 1024 + hd] = o;
}

// ---------------------------------------------------------------- launch
extern "C" void kernel_launch(void* const* d_in, const int* in_sizes, int n_in,
                              void* d_out, int out_size, void* d_ws, size_t ws_size,
                              hipStream_t stream) {
    const void* x     = d_in[0];
    const void* key   = d_in[1];
    const void* value = d_in[2];
    const int*  mask  = (const int*)d_in[3];
    const void* Wq    = d_in[4];
    const void* Wk    = d_in[5];
    const void* Wv    = d_in[6];
    const void* Wo    = d_in[7];
    const void* gamma = d_in[8];
    const void* beta  = d_in[9];

    // ws layout (65 MB), time-multiplexed (all concurrent uses disjoint):
    //  @1   xn [8MB]  (ln out; Q-gemm in)      -> after Q-gemm: o1b0@1..5, o1b1@5..9
    //  @9   kb [16MB] (conv out; K-gemm in)    -> after merged gemm: o0 [16MB f32]
    //  @25  vb [16MB] (conv out; V-gemm in)    -> after merged gemm: q@25..33 [8MB],
    //                                             o1b2@33..37, o1b3@37..41
    //  @41  vT [16MB] (V-gemm out; attn in)    -> after attn: ao@41..49 [8MB]
    //  @57  Wqt,Wkt,Wvt,Wot [2MB each]         -> after Q-gemm: mbits@57..58,
    //                                             la0@58, la1@58.25
    //  k (16MB bf16) lives in d_out until the final gemm overwrites it.
    char* ws = (char*)d_ws;
    int* flag = (int*)(ws);
    u16* xn   = (u16*)(ws + ( 1ull << 20));
    float* o1b0 = (float*)(ws + ( 1ull << 20));
    float* o1b1 = (float*)(ws + ( 5ull << 20));
    u16* kb   = (u16*)(ws + ( 9ull << 20));
    float* o0 = (float*)(ws + ( 9ull << 20));
    u16* vb   = (u16*)(ws + (25ull << 20));
    u16* q    = (u16*)(ws + (25ull << 20));
    float* o1b2 = (float*)(ws + (33ull << 20));
    float* o1b3 = (float*)(ws + (37ull << 20));
    u16* vT   = (u16*)(ws + (41ull << 20));
    u16* ao   = (u16*)(ws + (41ull << 20));
    u16* Wqt  = (u16*)(ws + (57ull << 20));
    u32* mbits= (u32*)(ws + (57ull << 20));
    float* la0  = (float*)(ws + (58ull << 20));
    float* la1  = (float*)(ws + (58ull << 20) + (256ull << 10));
    u16* Wkt  = (u16*)(ws + (59ull << 20));
    u16* Wvt  = (u16*)(ws + (61ull << 20));
    u16* Wot  = (u16*)(ws + (63ull << 20));
    u16* k    = (u16*)d_out;

    const float QSCALE = 0.125f * 1.44269504f;   // d^-0.5 * log2(e) for exp2 softmax

    detect_dtype<<<1, 256, 0, stream>>>((const u32*)x, flag);

    ln_kernel<<<4096, 256, 0, stream>>>(x, gamma, beta, xn, flag);

    dim3 tg4(16, 16, 4);
    transpose64x4<<<tg4, 256, 0, stream>>>(Wq, Wk, Wv, Wo, Wqt, Wkt, Wvt, Wot,
                                           1024, 1024, flag);

    conv_bf16_2<<<8192, 256, 0, stream>>>(key, value, kb, vb, flag, 4096);

    // merged V+K gemm: 1024 blocks -> 4 blocks/CU, tails overlap
    gemm128_vk<<<1024, 256, 0, stream>>>(vb, Wvt, vT, kb, Wkt, k);

    // Q-gemm (vb dead -> q@25..33)
    gemm128<<<256, 256, 0, stream>>>(xn, Wqt, q, 4096, 1024, 1024, flag, 0, QSCALE, 0, 4);

    // after Q-gemm (Wqt dead): pack mask into bits @57..58
    mask_bits<<<1024, 256, 0, stream>>>(mask, (u64*)mbits);

    attn_kernel<<<2048, 256, 0, stream>>>(q, k, vT, mbits,
                                          o0, o1b0, o1b1, o1b2, o1b3, la0, la1);

    combine_halves<<<4096, 256, 0, stream>>>(o0, o1b0, o1b1, o1b2, o1b3,
                                             la0, la1, ao);

    gemm128<<<256, 256, 0, stream>>>(ao, Wot, d_out, 4096, 1024, 1024, flag, 1, 1.0f, 0, 4);
}

// Round 6
// 343.492 us; speedup vs baseline: 1.1555x; 1.0191x over previous
//
#include <hip/hip_runtime.h>

typedef unsigned short u16;
typedef unsigned int u32;
typedef unsigned char u8;
typedef unsigned long long u64;

typedef __attribute__((ext_vector_type(8))) short bf16x8;
typedef __attribute__((ext_vector_type(4))) short bf16x4;
typedef __attribute__((ext_vector_type(4))) float f32x4;

__device__ __forceinline__ float bf2f(u16 u) {
    union { u32 i; float f; } v; v.i = ((u32)u) << 16; return v.f;
}
__device__ __forceinline__ u16 f2bf(float f) {
    union { float f; u32 i; } v; v.f = f;
    u32 r = v.i + 0x7fffu + ((v.i >> 16) & 1u);
    return (u16)(r >> 16);
}
// pack two f32 -> bf16x2 in one u32 (low = a, high = b) — software RNE (proven)
__device__ __forceinline__ u32 pkbf(float a, float b) {
    return (u32)f2bf(a) | ((u32)f2bf(b) << 16);
}
// raw v_exp_f32 (2^x). <=2 ULP vs OCML exp2f — negligible for softmax P.
__device__ __forceinline__ float fexp2(float x) { return __builtin_amdgcn_exp2f(x); }

// async global->LDS, 16B per lane; lds must be wave-uniform (lane*16 added by HW)
__device__ __forceinline__ void async16(u16* lds, const u16* g) {
    __builtin_amdgcn_global_load_lds(
        (const __attribute__((address_space(1))) void*)g,
        (__attribute__((address_space(3))) void*)lds, 16, 0, 0);
}

// ------------------------------------------------------------- dtype detect
__global__ __launch_bounds__(256) void detect_dtype(const u32* __restrict__ x,
                                                    int* __restrict__ flag) {
    int tid = threadIdx.x;
    int hits = 0;
    for (int i = 0; i < 4; ++i) {
        u32 w = x[tid * 4 + i];
        u32 e = (w >> 7) & 0xFFu;
        hits += (e >= 110u && e <= 131u) ? 1 : 0;
    }
    for (int off = 1; off < 64; off <<= 1) hits += __shfl_xor(hits, off, 64);
    __shared__ int red[4];
    int wave = tid >> 6, lane = tid & 63;
    if (lane == 0) red[wave] = hits;
    __syncthreads();
    if (tid == 0) flag[0] = (red[0] + red[1] + red[2] + red[3] > 512) ? 1 : 0;
}

// ------------------------------------------- convert pass (key+value fused)
__global__ __launch_bounds__(256) void conv_bf16_2(const void* __restrict__ src0,
                                                   const void* __restrict__ src1,
                                                   u16* __restrict__ dst0,
                                                   u16* __restrict__ dst1,
                                                   const int* __restrict__ flagp,
                                                   int half_blocks) {
    int flag = *flagp;
    const void* src = (blockIdx.x < (u32)half_blocks) ? src0 : src1;
    u16* dst = (blockIdx.x < (u32)half_blocks) ? dst0 : dst1;
    int blk = (blockIdx.x < (u32)half_blocks) ? blockIdx.x : (blockIdx.x - half_blocks);
    size_t i = (size_t)blk * 256 + threadIdx.x;
    if (flag) {
        ((uint4*)dst)[i] = ((const uint4*)src)[i];
    } else {
        const float4* s = (const float4*)src + i * 2;
        float4 f0 = s[0], f1 = s[1];
        u16 t[8];
        t[0] = f2bf(f0.x); t[1] = f2bf(f0.y); t[2] = f2bf(f0.z); t[3] = f2bf(f0.w);
        t[4] = f2bf(f1.x); t[5] = f2bf(f1.y); t[6] = f2bf(f1.z); t[7] = f2bf(f1.w);
        ((uint4*)dst)[i] = *(const uint4*)t;
    }
}

// ------------------------------------------------------------ mask -> bits
// keep-bit = (m == 0). __ballot bit l == lane l == kv (base+l), so each wave
// packs one q-row (2048 ints) into 32 u64 words, bit index == kv index.
__global__ __launch_bounds__(256) void mask_bits(const int* __restrict__ m,
                                                 u64* __restrict__ o) {
    int wid  = (blockIdx.x * 256 + threadIdx.x) >> 6;
    int lane = threadIdx.x & 63;
    size_t base = (size_t)wid * 2048;
    for (int it = 0; it < 8; ++it) {
        u64 b0 = __ballot(m[base + it * 256 +   0 + lane] == 0);
        u64 b1 = __ballot(m[base + it * 256 +  64 + lane] == 0);
        u64 b2 = __ballot(m[base + it * 256 + 128 + lane] == 0);
        u64 b3 = __ballot(m[base + it * 256 + 192 + lane] == 0);
        if (lane == 0) {
            size_t idx = (base + it * 256) >> 6;
            o[idx + 0] = b0; o[idx + 1] = b1; o[idx + 2] = b2; o[idx + 3] = b3;
        }
    }
}

// ---------------------------------------------------------------- LayerNorm
__global__ __launch_bounds__(256) void ln_kernel(const void* __restrict__ x_,
                                                 const void* __restrict__ g_,
                                                 const void* __restrict__ b_,
                                                 u16* __restrict__ out,
                                                 const int* __restrict__ flagp) {
    int flag = *flagp;
    int row = blockIdx.x;
    int tid = threadIdx.x;
    float v[4];
    if (flag) {
        const u16* xr = (const u16*)x_ + (size_t)row * 1024;
        uint2 d = *(const uint2*)&xr[tid * 4];
        v[0] = bf2f((u16)(d.x & 0xffff));
        v[1] = bf2f((u16)(d.x >> 16));
        v[2] = bf2f((u16)(d.y & 0xffff));
        v[3] = bf2f((u16)(d.y >> 16));
    } else {
        const float* xr = (const float*)x_ + (size_t)row * 1024;
        float4 d = *(const float4*)&xr[tid * 4];
        v[0] = d.x; v[1] = d.y; v[2] = d.z; v[3] = d.w;
    }
    float s  = v[0] + v[1] + v[2] + v[3];
    float ss = v[0]*v[0] + v[1]*v[1] + v[2]*v[2] + v[3]*v[3];
    for (int off = 1; off < 64; off <<= 1) {
        s  += __shfl_xor(s,  off, 64);
        ss += __shfl_xor(ss, off, 64);
    }
    __shared__ float red[8];
    int wave = tid >> 6, lane = tid & 63;
    if (lane == 0) { red[wave] = s; red[4 + wave] = ss; }
    __syncthreads();
    s  = red[0] + red[1] + red[2] + red[3];
    ss = red[4] + red[5] + red[6] + red[7];
    float mu   = s * (1.0f / 1024.0f);
    float var  = ss * (1.0f / 1024.0f) - mu * mu;
    float rstd = rsqrtf(var + 1e-5f);
    u16 r01[4];
    for (int j = 0; j < 4; ++j) {
        float g, bb;
        if (flag) { g = bf2f(((const u16*)g_)[tid * 4 + j]); bb = bf2f(((const u16*)b_)[tid * 4 + j]); }
        else      { g = ((const float*)g_)[tid * 4 + j];     bb = ((const float*)b_)[tid * 4 + j]; }
        r01[j] = f2bf((v[j] - mu) * rstd * g + bb);
    }
    uint2 o;
    o.x = (u32)r01[0] | ((u32)r01[1] << 16);
    o.y = (u32)r01[2] | ((u32)r01[3] << 16);
    *(uint2*)&out[(size_t)row * 1024 + tid * 4] = o;
}

// ------------------------------------------- Transpose (4 weights, 1 launch)
__global__ __launch_bounds__(256) void transpose64x4(const void* __restrict__ s0,
                                                     const void* __restrict__ s1,
                                                     const void* __restrict__ s2,
                                                     const void* __restrict__ s3,
                                                     u16* __restrict__ d0,
                                                     u16* __restrict__ d1,
                                                     u16* __restrict__ d2,
                                                     u16* __restrict__ d3,
                                                     int rows, int cols,
                                                     const int* __restrict__ flagp) {
    __shared__ u16 t[64][65];
    int flag = *flagp;
    const void* src_ = (blockIdx.z == 0) ? s0 : (blockIdx.z == 1) ? s1 :
                       (blockIdx.z == 2) ? s2 : s3;
    u16* dst = (blockIdx.z == 0) ? d0 : (blockIdx.z == 1) ? d1 :
               (blockIdx.z == 2) ? d2 : d3;
    int bx = blockIdx.x * 64;
    int by = blockIdx.y * 64;
    int tid = threadIdx.x;
    for (int i = 0; i < 16; ++i) {
        int r = i * 4 + (tid >> 6);
        int c = tid & 63;
        size_t idx = (size_t)(by + r) * cols + bx + c;
        t[r][c] = flag ? ((const u16*)src_)[idx] : f2bf(((const float*)src_)[idx]);
    }
    __syncthreads();
    for (int i = 0; i < 16; ++i) {
        int r = i * 4 + (tid >> 6);
        int c = tid & 63;
        dst[(size_t)(bx + r) * rows + by + c] = t[c][r];
    }
}

// ------------------------------------------------------- GEMM 128x128 (B^T)
// __launch_bounds__(256,3): cap VGPR ~170 -> 3 blocks/CU (m97 reference: same
// structure fits 164 VGPR at 874 TF). (256,2) allowed up to 256 VGPR -> was
// VGPR-capped at 2 blocks/CU, the round-4 null.
__global__ __launch_bounds__(256, 3) void gemm128(const u16* __restrict__ A,
                                                  const u16* __restrict__ Bt,
                                                  void* __restrict__ C_,
                                                  int M, int N, int K,
                                                  const int* __restrict__ flagp,
                                                  int c_flagged, float cscale,
                                                  int vt_mode, int mdiv) {
    __shared__ u16 As[128 * 64];
    __shared__ u16 Bs[128 * 64];
    int flag = *flagp;
    bool c_bf16 = c_flagged ? (flag != 0) : true;

    int id  = blockIdx.x;
    int j   = id >> 3;
    int gy  = (id & 7) + 8 * (j % mdiv);
    int bnt = j / mdiv;

    int tid  = threadIdx.x;
    int wave = tid >> 6, lane = tid & 63;
    int quad = lane >> 4, l16 = lane & 15;
    size_t bm = (size_t)gy * 128;
    size_t bn = (size_t)bnt * 128;
    int wm = (wave >> 1) * 64, wn = (wave & 1) * 64;

    int lr  = lane >> 3;
    int csw = (lane & 7) ^ lr;
    const u16* Ag = A  + (bm + wave * 32 + lr) * (size_t)K + csw * 8;
    const u16* Bg = Bt + (bn + wave * 32 + lr) * (size_t)K + csw * 8;
    u16* Al = &As[(wave * 32) * 64];
    u16* Bl = &Bs[(wave * 32) * 64];

    f32x4 acc[4][4];
#pragma unroll
    for (int i = 0; i < 4; ++i)
#pragma unroll
        for (int jj = 0; jj < 4; ++jj)
            acc[i][jj] = (f32x4){0.f, 0.f, 0.f, 0.f};

    int rsw = l16 & 7;

    for (int k0 = 0; k0 < K; k0 += 64) {
        __syncthreads();
#pragma unroll
        for (int i = 0; i < 4; ++i) {
            async16(Al + i * 8 * 64, Ag + (size_t)i * 8 * K + k0);
            async16(Bl + i * 8 * 64, Bg + (size_t)i * 8 * K + k0);
        }
        __syncthreads();

#pragma unroll
        for (int ks = 0; ks < 2; ++ks) {
            int chunk = ((ks << 2) | quad) ^ rsw;
            bf16x8 af[4], bfr[4];
#pragma unroll
            for (int mi = 0; mi < 4; ++mi)
                af[mi]  = *(const bf16x8*)&As[(wm + mi * 16 + l16) * 64 + chunk * 8];
#pragma unroll
            for (int ni = 0; ni < 4; ++ni)
                bfr[ni] = *(const bf16x8*)&Bs[(wn + ni * 16 + l16) * 64 + chunk * 8];
#pragma unroll
            for (int mi = 0; mi < 4; ++mi)
#pragma unroll
                for (int ni = 0; ni < 4; ++ni)
                    acc[mi][ni] = __builtin_amdgcn_mfma_f32_16x16x32_bf16(
                        af[mi], bfr[ni], acc[mi][ni], 0, 0, 0);
        }
    }

    if (vt_mode) {
        u16* C = (u16*)C_;
#pragma unroll
        for (int mi = 0; mi < 4; ++mi)
#pragma unroll
            for (int ni = 0; ni < 4; ++ni) {
                size_t m = bm + wm + mi * 16 + quad * 4;
                size_t n = bn + wn + ni * 16 + l16;
                size_t bb = m >> 11, kv = m & 2047;
                size_t hh = n >> 6,  d  = n & 63;
                u16 t4[4];
#pragma unroll
                for (int r = 0; r < 4; ++r) t4[r] = f2bf(acc[mi][ni][r]);
                *(uint2*)&C[((bb * 16 + hh) * 64 + d) * 2048 + kv] = *(const uint2*)t4;
            }
    } else {
#pragma unroll
        for (int mi = 0; mi < 4; ++mi)
#pragma unroll
            for (int ni = 0; ni < 4; ++ni)
#pragma unroll
                for (int r = 0; r < 4; ++r) {
                    size_t row = bm + wm + mi * 16 + quad * 4 + r;
                    size_t col = bn + wn + ni * 16 + l16;
                    float val = acc[mi][ni][r] * cscale;
                    if (c_bf16) ((u16*)C_)[row * N + col]   = f2bf(val);
                    else        ((float*)C_)[row * N + col] = val;
                }
    }
}

// ----------------------------------- Merged V-GEMM + K-GEMM (one dispatch)
// Blocks 0..511: V-gemm (vb x Wvt -> vT, vt_mode epilogue).
// Blocks 512..1023: K-gemm (kb x Wkt -> k, plain bf16 epilogue).
// 1024 blocks; __launch_bounds__(256,3) -> 3 blocks/CU (VGPR-capped; see gemm128).
__global__ __launch_bounds__(256, 3) void gemm128_vk(const u16* __restrict__ A0,
                                                     const u16* __restrict__ Bt0,
                                                     u16* __restrict__ C0,
                                                     const u16* __restrict__ A1,
                                                     const u16* __restrict__ Bt1,
                                                     u16* __restrict__ C1) {
    __shared__ u16 As[128 * 64];
    __shared__ u16 Bs[128 * 64];
    const int N = 1024, K = 1024, mdiv = 8;

    int id  = blockIdx.x;
    int seg = id >> 9;                 // 0 = V, 1 = K
    int lid = id & 511;
    const u16* A  = seg ? A1 : A0;
    const u16* Bt = seg ? Bt1 : Bt0;

    int j   = lid >> 3;
    int gy  = (lid & 7) + 8 * (j % mdiv);
    int bnt = j / mdiv;

    int tid  = threadIdx.x;
    int wave = tid >> 6, lane = tid & 63;
    int quad = lane >> 4, l16 = lane & 15;
    size_t bm = (size_t)gy * 128;
    size_t bn = (size_t)bnt * 128;
    int wm = (wave >> 1) * 64, wn = (wave & 1) * 64;

    int lr  = lane >> 3;
    int csw = (lane & 7) ^ lr;
    const u16* Ag = A  + (bm + wave * 32 + lr) * (size_t)K + csw * 8;
    const u16* Bg = Bt + (bn + wave * 32 + lr) * (size_t)K + csw * 8;
    u16* Al = &As[(wave * 32) * 64];
    u16* Bl = &Bs[(wave * 32) * 64];

    f32x4 acc[4][4];
#pragma unroll
    for (int i = 0; i < 4; ++i)
#pragma unroll
        for (int jj = 0; jj < 4; ++jj)
            acc[i][jj] = (f32x4){0.f, 0.f, 0.f, 0.f};

    int rsw = l16 & 7;

    for (int k0 = 0; k0 < K; k0 += 64) {
        __syncthreads();
#pragma unroll
        for (int i = 0; i < 4; ++i) {
            async16(Al + i * 8 * 64, Ag + (size_t)i * 8 * K + k0);
            async16(Bl + i * 8 * 64, Bg + (size_t)i * 8 * K + k0);
        }
        __syncthreads();

#pragma unroll
        for (int ks = 0; ks < 2; ++ks) {
            int chunk = ((ks << 2) | quad) ^ rsw;
            bf16x8 af[4], bfr[4];
#pragma unroll
            for (int mi = 0; mi < 4; ++mi)
                af[mi]  = *(const bf16x8*)&As[(wm + mi * 16 + l16) * 64 + chunk * 8];
#pragma unroll
            for (int ni = 0; ni < 4; ++ni)
                bfr[ni] = *(const bf16x8*)&Bs[(wn + ni * 16 + l16) * 64 + chunk * 8];
#pragma unroll
            for (int mi = 0; mi < 4; ++mi)
#pragma unroll
                for (int ni = 0; ni < 4; ++ni)
                    acc[mi][ni] = __builtin_amdgcn_mfma_f32_16x16x32_bf16(
                        af[mi], bfr[ni], acc[mi][ni], 0, 0, 0);
        }
    }

    if (!seg) {
        // V: transposed per-head layout [b][h][d][kv]
        u16* C = C0;
#pragma unroll
        for (int mi = 0; mi < 4; ++mi)
#pragma unroll
            for (int ni = 0; ni < 4; ++ni) {
                size_t m = bm + wm + mi * 16 + quad * 4;
                size_t n = bn + wn + ni * 16 + l16;
                size_t bb = m >> 11, kv = m & 2047;
                size_t hh = n >> 6,  d  = n & 63;
                u16 t4[4];
#pragma unroll
                for (int r = 0; r < 4; ++r) t4[r] = f2bf(acc[mi][ni][r]);
                *(uint2*)&C[((bb * 16 + hh) * 64 + d) * 2048 + kv] = *(const uint2*)t4;
            }
    } else {
        u16* C = C1;
#pragma unroll
        for (int mi = 0; mi < 4; ++mi)
#pragma unroll
            for (int ni = 0; ni < 4; ++ni)
#pragma unroll
                for (int r = 0; r < 4; ++r) {
                    size_t row = bm + wm + mi * 16 + quad * 4 + r;
                    size_t col = bn + wn + ni * 16 + l16;
                    C[row * N + col] = f2bf(acc[mi][ni][r]);
                }
    }
}

// ---------------------------------------------------------------- Attention
// S^T formulation, XCD-grouped, async XOR-swizzled staging, 2-way KV-split
// (exp2 softmax is additive: halves emit un-normalized f32 partials; combine
// divides by l0+l1). Grid 2048. Mask bit-packed.
__global__ __launch_bounds__(256) void attn_kernel(const u16* __restrict__ qg,
                                                   const u16* __restrict__ kg,
                                                   const u16* __restrict__ vtg,
                                                   const u32* __restrict__ mbits,
                                                   float* __restrict__ o0,
                                                   float* __restrict__ o1b0,
                                                   float* __restrict__ o1b1,
                                                   float* __restrict__ o1b2,
                                                   float* __restrict__ o1b3,
                                                   float* __restrict__ lacc0,
                                                   float* __restrict__ lacc1) {
    __shared__ u16 Ks[64 * 64];
    __shared__ u16 Vst[64 * 64];     // [d][kv], swizzled

    const int NQc = 1024, NKVc = 2048, HD = 1024;
    int id = blockIdx.x;
    int j  = id >> 3;
    int qt2 = j >> 3;                      // [0,32)
    int half = qt2 >> 4;                   // KV half
    int qt = qt2 & 15;                     // [0,16)
    int g  = (id & 7) + ((j & 7) << 3);    // [0,64) (b,h) group; xcd = id&7
    int h  = g & 15;
    int b  = g >> 4;

    int tid  = threadIdx.x;
    int wave = tid >> 6, lane = tid & 63;
    int quad = lane >> 4, l16 = lane & 15;
    int q0 = qt * 64;

    // Q fragment (B-operand: n=q=l16, k=d=quad*8+j) straight from global
    const u16* qrow = qg + ((size_t)b * NQc + q0 + wave * 16 + l16) * HD + h * 64;
    bf16x8 aq0 = *(const bf16x8*)&qrow[quad * 8];
    bf16x8 aq1 = *(const bf16x8*)&qrow[32 + quad * 8];

    // staging source addressing (per lane): row lr in 8-row group, chunk swizzle
    int lr  = lane >> 3;                   // [0,8)
    int csw = (lane & 7) ^ lr;             // source 16B chunk for phys lane&7
    const u16* kbase = kg  + ((size_t)b * NKVc + wave * 8 + lr) * HD + h * 64 + csw * 8;
    const u16* vbase = vtg + (((size_t)b * 16 + h) * 64 + wave * 8 + lr) * (size_t)NKVc + csw * 8;
    u16* kl = Ks  + (wave * 8) * 64;
    u16* vl = Vst + (wave * 8) * 64;

    f32x4 O[4], lacc;
#pragma unroll
    for (int dt = 0; dt < 4; ++dt) O[dt] = (f32x4){0.f, 0.f, 0.f, 0.f};
    lacc = (f32x4){0.f, 0.f, 0.f, 0.f};

    bf16x4 ones4;
#pragma unroll
    for (int jj = 0; jj < 4; ++jj) ones4[jj] = (short)0x3F80;

    // bit-mask row: 64 u32 per q-row, bit index == kv index
    const u32* mrowb = mbits + ((size_t)b * NQc + q0 + wave * 16 + l16) * 64;

    int l7 = l16 & 7;
    int kvbeg = half << 10;

    for (int kv0 = kvbeg; kv0 < kvbeg + 1024; kv0 += 64) {
        __syncthreads();
#pragma unroll
        for (int i = 0; i < 2; ++i) {
            // K rows kv0+i*32+wave*8+lr ; V (d-rows) i*32+wave*8+lr, cols kv0
            async16(kl + i * 32 * 64, kbase + ((size_t)kv0 + i * 32) * HD);
            async16(vl + i * 32 * 64, vbase + (size_t)(i * 32) * NKVc + kv0);
        }
        __syncthreads();

        uint2 bw = *(const uint2*)&mrowb[kv0 >> 5];   // bits kv0..kv0+63

        // per nt: S^T tile -> exp2 -> mask -> bf16x4 P^T fragment
        bf16x4 pfr[4];
#pragma unroll
        for (int nt = 0; nt < 4; ++nt) {
            const u16* krow = Ks + (nt * 16 + l16) * 64;
            bf16x8 bk0 = *(const bf16x8*)&krow[(quad ^ l7) * 8];
            bf16x8 bk1 = *(const bf16x8*)&krow[((4 + quad) ^ l7) * 8];
            f32x4 st = (f32x4){0.f, 0.f, 0.f, 0.f};
            st = __builtin_amdgcn_mfma_f32_16x16x32_bf16(bk0, aq0, st, 0, 0, 0);
            st = __builtin_amdgcn_mfma_f32_16x16x32_bf16(bk1, aq1, st, 0, 0, 0);

            u32 w  = (nt < 2) ? bw.x : bw.y;
            u32 m4 = (w >> (((nt & 1) << 4) + (quad << 2))) & 0xFu;
            u32 m01 = ((m4 & 1u) ? 0xFFFFu : 0u) | ((m4 & 2u) ? 0xFFFF0000u : 0u);
            u32 m23 = ((m4 & 4u) ? 0xFFFFu : 0u) | ((m4 & 8u) ? 0xFFFF0000u : 0u);
            u32 p01 = pkbf(fexp2(st[0]), fexp2(st[1])) & m01;
            u32 p23 = pkbf(fexp2(st[2]), fexp2(st[3])) & m23;
            uint2 pu; pu.x = p01; pu.y = p23;
            pfr[nt] = *(const bf16x4*)&pu;

            lacc = __builtin_amdgcn_mfma_f32_16x16x16bf16_1k(ones4, pfr[nt], lacc, 0, 0, 0);
        }

        // O^T += V^T . P^T   (A-frag: d-row = dt*16+l16, kv = kvs*16+quad*4)
#pragma unroll
        for (int dt = 0; dt < 4; ++dt) {
            const u16* vrow = Vst + (dt * 16 + l16) * 64;
#pragma unroll
            for (int kvs = 0; kvs < 4; ++kvs) {
                int gran = ((kvs << 1) | (quad >> 1)) ^ l7;   // 16B granule (2 per read-half)
                bf16x4 av = *(const bf16x4*)&vrow[gran * 8 + (quad & 1) * 4];
                O[dt] = __builtin_amdgcn_mfma_f32_16x16x16bf16_1k(av, pfr[kvs], O[dt], 0, 0, 0);
            }
        }
    }

    // epilogue: un-normalized f32 partials. o0 layout [b][q][hd]; o1 per-b [q][hd].
    int qi = q0 + wave * 16 + l16;
    float* opart = half ? (b == 0 ? o1b0 : b == 1 ? o1b1 : b == 2 ? o1b2 : o1b3) : o0;
    size_t rbase = half ? (size_t)qi : ((size_t)b * NQc + qi);
    float* orow = opart + rbase * 1024 + h * 64;
#pragma unroll
    for (int dt = 0; dt < 4; ++dt)
        *(float4*)&orow[dt * 16 + quad * 4] = (float4){O[dt][0], O[dt][1], O[dt][2], O[dt][3]};

    float* lp = half ? lacc1 : lacc0;
    if (quad == 0) lp[((size_t)b * 16 + h) * 1024 + qi] = lacc[0];
}

// ------------------------------------------------------------- combine halves
__global__ __launch_bounds__(256) void combine_halves(const float* __restrict__ p0,
                                                      const float* __restrict__ p1b0,
                                                      const float* __restrict__ p1b1,
                                                      const float* __restrict__ p1b2,
                                                      const float* __restrict__ p1b3,
                                                      const float* __restrict__ l0,
                                                      const float* __restrict__ l1,
                                                      u16* __restrict__ ao) {
    int row = blockIdx.x;                 // b*1024 + q
    int b = row >> 10, qq = row & 1023;
    const float* p1 = (b == 0) ? p1b0 : (b == 1) ? p1b1 : (b == 2) ? p1b2 : p1b3;
    int tid = threadIdx.x;
    int hd = tid * 4;
    int h  = hd >> 6;
    float4 a = *(const float4*)&p0[(size_t)row * 1024 + hd];
    float4 c = *(const float4*)&p1[(size_t)qq  * 1024 + hd];
    size_t li = ((size_t)b * 16 + h) * 1024 + qq;
    float inv = 1.0f / (l0[li] + l1[li]);
    uint2 o;
    o.x = (u32)f2bf((a.x + c.x) * inv) | ((u32)f2bf((a.y + c.y) * inv) << 16);
    o.y = (u32)f2bf((a.z + c.z) * inv) | ((u32)f2bf((a.w + c.w) * inv) << 16);
    *(uint2*)&ao[(size_t)row * 1024 + hd] = o;
}

// ---------------------------------------------------------------- launch
extern "C" void kernel_launch(void* const* d_in, const int* in_sizes, int n_in,
                              void* d_out, int out_size, void* d_ws, size_t ws_size,
                              hipStream_t stream) {
    const void* x     = d_in[0];
    const void* key   = d_in[1];
    const void* value = d_in[2];
    const int*  mask  = (const int*)d_in[3];
    const void* Wq    = d_in[4];
    const void* Wk    = d_in[5];
    const void* Wv    = d_in[6];
    const void* Wo    = d_in[7];
    const void* gamma = d_in[8];
    const void* beta  = d_in[9];

    // ws layout (65 MB), time-multiplexed (all concurrent uses disjoint):
    //  @1   xn [8MB]  (ln out; Q-gemm in)      -> after Q-gemm: o1b0@1..5, o1b1@5..9
    //  @9   kb [16MB] (conv out; K-gemm in)    -> after merged gemm: o0 [16MB f32]
    //  @25  vb [16MB] (conv out; V-gemm in)    -> after merged gemm: q@25..33 [8MB],
    //                                             o1b2@33..37, o1b3@37..41
    //  @41  vT [16MB] (V-gemm out; attn in)    -> after attn: ao@41..49 [8MB]
    //  @57  Wqt,Wkt,Wvt,Wot [2MB each]         -> after Q-gemm: mbits@57..58,
    //                                             la0@58, la1@58.25
    //  k (16MB bf16) lives in d_out until the final gemm overwrites it.
    char* ws = (char*)d_ws;
    int* flag = (int*)(ws);
    u16* xn   = (u16*)(ws + ( 1ull << 20));
    float* o1b0 = (float*)(ws + ( 1ull << 20));
    float* o1b1 = (float*)(ws + ( 5ull << 20));
    u16* kb   = (u16*)(ws + ( 9ull << 20));
    float* o0 = (float*)(ws + ( 9ull << 20));
    u16* vb   = (u16*)(ws + (25ull << 20));
    u16* q    = (u16*)(ws + (25ull << 20));
    float* o1b2 = (float*)(ws + (33ull << 20));
    float* o1b3 = (float*)(ws + (37ull << 20));
    u16* vT   = (u16*)(ws + (41ull << 20));
    u16* ao   = (u16*)(ws + (41ull << 20));
    u16* Wqt  = (u16*)(ws + (57ull << 20));
    u32* mbits= (u32*)(ws + (57ull << 20));
    float* la0  = (float*)(ws + (58ull << 20));
    float* la1  = (float*)(ws + (58ull << 20) + (256ull << 10));
    u16* Wkt  = (u16*)(ws + (59ull << 20));
    u16* Wvt  = (u16*)(ws + (61ull << 20));
    u16* Wot  = (u16*)(ws + (63ull << 20));
    u16* k    = (u16*)d_out;

    const float QSCALE = 0.125f * 1.44269504f;   // d^-0.5 * log2(e) for exp2 softmax

    detect_dtype<<<1, 256, 0, stream>>>((const u32*)x, flag);

    ln_kernel<<<4096, 256, 0, stream>>>(x, gamma, beta, xn, flag);

    dim3 tg4(16, 16, 4);
    transpose64x4<<<tg4, 256, 0, stream>>>(Wq, Wk, Wv, Wo, Wqt, Wkt, Wvt, Wot,
                                           1024, 1024, flag);

    conv_bf16_2<<<8192, 256, 0, stream>>>(key, value, kb, vb, flag, 4096);

    // merged V+K gemm: 1024 blocks, 3 blocks/CU (launch_bounds-capped VGPR)
    gemm128_vk<<<1024, 256, 0, stream>>>(vb, Wvt, vT, kb, Wkt, k);

    // Q-gemm (vb dead -> q@25..33)
    gemm128<<<256, 256, 0, stream>>>(xn, Wqt, q, 4096, 1024, 1024, flag, 0, QSCALE, 0, 4);

    // after Q-gemm (Wqt dead): pack mask into bits @57..58
    mask_bits<<<1024, 256, 0, stream>>>(mask, (u64*)mbits);

    attn_kernel<<<2048, 256, 0, stream>>>(q, k, vT, mbits,
                                          o0, o1b0, o1b1, o1b2, o1b3, la0, la1);

    combine_halves<<<4096, 256, 0, stream>>>(o0, o1b0, o1b1, o1b2, o1b3,
                                             la0, la1, ao);

    gemm128<<<256, 256, 0, stream>>>(ao, Wot, d_out, 4096, 1024, 1024, flag, 1, 1.0f, 0, 4);
}

// Round 7
// 340.741 us; speedup vs baseline: 1.1649x; 1.0081x over previous
//
#include <hip/hip_runtime.h>

typedef unsigned short u16;
typedef unsigned int u32;
typedef unsigned char u8;
typedef unsigned long long u64;

typedef __attribute__((ext_vector_type(8))) short bf16x8;
typedef __attribute__((ext_vector_type(4))) short bf16x4;
typedef __attribute__((ext_vector_type(4))) float f32x4;

__device__ __forceinline__ float bf2f(u16 u) {
    union { u32 i; float f; } v; v.i = ((u32)u) << 16; return v.f;
}
__device__ __forceinline__ u16 f2bf(float f) {
    union { float f; u32 i; } v; v.f = f;
    u32 r = v.i + 0x7fffu + ((v.i >> 16) & 1u);
    return (u16)(r >> 16);
}
// pack two f32 -> bf16x2 in one u32 (low = a, high = b) — software RNE (proven)
__device__ __forceinline__ u32 pkbf(float a, float b) {
    return (u32)f2bf(a) | ((u32)f2bf(b) << 16);
}
// raw v_exp_f32 (2^x). <=2 ULP vs OCML exp2f — negligible for softmax P.
__device__ __forceinline__ float fexp2(float x) { return __builtin_amdgcn_exp2f(x); }

// async global->LDS, 16B per lane; lds must be wave-uniform (lane*16 added by HW)
__device__ __forceinline__ void async16(u16* lds, const u16* g) {
    __builtin_amdgcn_global_load_lds(
        (const __attribute__((address_space(1))) void*)g,
        (__attribute__((address_space(3))) void*)lds, 16, 0, 0);
}

// =============================================================== PREP
// One dispatch: [0..4096) LayerNorm rows, [4096..5120) weight transpose,
// [5120..13312) key/value bf16 convert, block 13312 writes flag.
// Every block self-detects dtype on x's first 4KB (identical words+threshold
// as the old detect_dtype kernel -> bit-identical decision; L2-broadcast).
__global__ __launch_bounds__(256) void prep_kernel(
        const u32* __restrict__ xw,          // x as words (for detect)
        const void* __restrict__ x_,
        const void* __restrict__ key,
        const void* __restrict__ value,
        const void* __restrict__ g_,
        const void* __restrict__ b_,
        const void* __restrict__ Wq, const void* __restrict__ Wk,
        const void* __restrict__ Wv, const void* __restrict__ Wo,
        u16* __restrict__ xn,
        u16* __restrict__ kb, u16* __restrict__ vb,
        u16* __restrict__ Wqt, u16* __restrict__ Wkt,
        u16* __restrict__ Wvt, u16* __restrict__ Wot,
        int* __restrict__ flagp) {
    __shared__ int  redi[4];
    __shared__ float redf[8];
    __shared__ u16 tsh[64][65];

    int tid = threadIdx.x;
    int wave = tid >> 6, lane = tid & 63;

    // --- self-detect on x[0..1023] words (matches old detect_dtype exactly)
    int hits = 0;
    for (int i = 0; i < 4; ++i) {
        u32 w = xw[tid * 4 + i];
        u32 e = (w >> 7) & 0xFFu;
        hits += (e >= 110u && e <= 131u) ? 1 : 0;
    }
    for (int off = 1; off < 64; off <<= 1) hits += __shfl_xor(hits, off, 64);
    if (lane == 0) redi[wave] = hits;
    __syncthreads();
    int flag = (redi[0] + redi[1] + redi[2] + redi[3] > 512) ? 1 : 0;

    int blk = blockIdx.x;

    if (blk == 13312) {                       // flag writer for later gemms
        if (tid == 0) flagp[0] = flag;
        return;
    }

    if (blk < 4096) {
        // ---------------- LayerNorm row
        int row = blk;
        float v[4];
        if (flag) {
            const u16* xr = (const u16*)x_ + (size_t)row * 1024;
            uint2 d = *(const uint2*)&xr[tid * 4];
            v[0] = bf2f((u16)(d.x & 0xffff));
            v[1] = bf2f((u16)(d.x >> 16));
            v[2] = bf2f((u16)(d.y & 0xffff));
            v[3] = bf2f((u16)(d.y >> 16));
        } else {
            const float* xr = (const float*)x_ + (size_t)row * 1024;
            float4 d = *(const float4*)&xr[tid * 4];
            v[0] = d.x; v[1] = d.y; v[2] = d.z; v[3] = d.w;
        }
        float s  = v[0] + v[1] + v[2] + v[3];
        float ss = v[0]*v[0] + v[1]*v[1] + v[2]*v[2] + v[3]*v[3];
        for (int off = 1; off < 64; off <<= 1) {
            s  += __shfl_xor(s,  off, 64);
            ss += __shfl_xor(ss, off, 64);
        }
        if (lane == 0) { redf[wave] = s; redf[4 + wave] = ss; }
        __syncthreads();
        s  = redf[0] + redf[1] + redf[2] + redf[3];
        ss = redf[4] + redf[5] + redf[6] + redf[7];
        float mu   = s * (1.0f / 1024.0f);
        float var  = ss * (1.0f / 1024.0f) - mu * mu;
        float rstd = rsqrtf(var + 1e-5f);
        u16 r01[4];
        for (int j = 0; j < 4; ++j) {
            float g, bb;
            if (flag) { g = bf2f(((const u16*)g_)[tid * 4 + j]); bb = bf2f(((const u16*)b_)[tid * 4 + j]); }
            else      { g = ((const float*)g_)[tid * 4 + j];     bb = ((const float*)b_)[tid * 4 + j]; }
            r01[j] = f2bf((v[j] - mu) * rstd * g + bb);
        }
        uint2 o;
        o.x = (u32)r01[0] | ((u32)r01[1] << 16);
        o.y = (u32)r01[2] | ((u32)r01[3] << 16);
        *(uint2*)&xn[(size_t)row * 1024 + tid * 4] = o;
    } else if (blk < 5120) {
        // ---------------- weight transpose (64x64 tile)
        int t = blk - 4096;
        int w = t >> 8;                       // which weight
        int tt = t & 255;
        const void* src_ = (w == 0) ? Wq : (w == 1) ? Wk : (w == 2) ? Wv : Wo;
        u16* dst = (w == 0) ? Wqt : (w == 1) ? Wkt : (w == 2) ? Wvt : Wot;
        int bx = (tt & 15) * 64;
        int by = (tt >> 4) * 64;
        const int rows = 1024, cols = 1024;
        for (int i = 0; i < 16; ++i) {
            int r = i * 4 + (tid >> 6);
            int c = tid & 63;
            size_t idx = (size_t)(by + r) * cols + bx + c;
            tsh[r][c] = flag ? ((const u16*)src_)[idx] : f2bf(((const float*)src_)[idx]);
        }
        __syncthreads();
        for (int i = 0; i < 16; ++i) {
            int r = i * 4 + (tid >> 6);
            int c = tid & 63;
            dst[(size_t)(bx + r) * rows + by + c] = tsh[c][r];
        }
    } else {
        // ---------------- key/value -> bf16
        int cblk = blk - 5120;
        const void* src = (cblk < 4096) ? key : value;
        u16* dst = (cblk < 4096) ? kb : vb;
        int b2 = (cblk < 4096) ? cblk : (cblk - 4096);
        size_t i = (size_t)b2 * 256 + tid;
        if (flag) {
            ((uint4*)dst)[i] = ((const uint4*)src)[i];
        } else {
            const float4* s4 = (const float4*)src + i * 2;
            float4 f0 = s4[0], f1 = s4[1];
            u16 t8[8];
            t8[0] = f2bf(f0.x); t8[1] = f2bf(f0.y); t8[2] = f2bf(f0.z); t8[3] = f2bf(f0.w);
            t8[4] = f2bf(f1.x); t8[5] = f2bf(f1.y); t8[6] = f2bf(f1.z); t8[7] = f2bf(f1.w);
            ((uint4*)dst)[i] = *(const uint4*)t8;
        }
    }
}

// ------------------------------------------------------- GEMM 128x128 (B^T)
// __launch_bounds__(256,3): cap VGPR ~170 -> 3 blocks/CU.
__global__ __launch_bounds__(256, 3) void gemm128(const u16* __restrict__ A,
                                                  const u16* __restrict__ Bt,
                                                  void* __restrict__ C_,
                                                  int M, int N, int K,
                                                  const int* __restrict__ flagp,
                                                  int c_flagged, float cscale,
                                                  int vt_mode, int mdiv) {
    __shared__ u16 As[128 * 64];
    __shared__ u16 Bs[128 * 64];
    int flag = *flagp;
    bool c_bf16 = c_flagged ? (flag != 0) : true;

    int id  = blockIdx.x;
    int j   = id >> 3;
    int gy  = (id & 7) + 8 * (j % mdiv);
    int bnt = j / mdiv;

    int tid  = threadIdx.x;
    int wave = tid >> 6, lane = tid & 63;
    int quad = lane >> 4, l16 = lane & 15;
    size_t bm = (size_t)gy * 128;
    size_t bn = (size_t)bnt * 128;
    int wm = (wave >> 1) * 64, wn = (wave & 1) * 64;

    int lr  = lane >> 3;
    int csw = (lane & 7) ^ lr;
    const u16* Ag = A  + (bm + wave * 32 + lr) * (size_t)K + csw * 8;
    const u16* Bg = Bt + (bn + wave * 32 + lr) * (size_t)K + csw * 8;
    u16* Al = &As[(wave * 32) * 64];
    u16* Bl = &Bs[(wave * 32) * 64];

    f32x4 acc[4][4];
#pragma unroll
    for (int i = 0; i < 4; ++i)
#pragma unroll
        for (int jj = 0; jj < 4; ++jj)
            acc[i][jj] = (f32x4){0.f, 0.f, 0.f, 0.f};

    int rsw = l16 & 7;

    for (int k0 = 0; k0 < K; k0 += 64) {
        __syncthreads();
#pragma unroll
        for (int i = 0; i < 4; ++i) {
            async16(Al + i * 8 * 64, Ag + (size_t)i * 8 * K + k0);
            async16(Bl + i * 8 * 64, Bg + (size_t)i * 8 * K + k0);
        }
        __syncthreads();

#pragma unroll
        for (int ks = 0; ks < 2; ++ks) {
            int chunk = ((ks << 2) | quad) ^ rsw;
            bf16x8 af[4], bfr[4];
#pragma unroll
            for (int mi = 0; mi < 4; ++mi)
                af[mi]  = *(const bf16x8*)&As[(wm + mi * 16 + l16) * 64 + chunk * 8];
#pragma unroll
            for (int ni = 0; ni < 4; ++ni)
                bfr[ni] = *(const bf16x8*)&Bs[(wn + ni * 16 + l16) * 64 + chunk * 8];
#pragma unroll
            for (int mi = 0; mi < 4; ++mi)
#pragma unroll
                for (int ni = 0; ni < 4; ++ni)
                    acc[mi][ni] = __builtin_amdgcn_mfma_f32_16x16x32_bf16(
                        af[mi], bfr[ni], acc[mi][ni], 0, 0, 0);
        }
    }

    if (vt_mode) {
        u16* C = (u16*)C_;
#pragma unroll
        for (int mi = 0; mi < 4; ++mi)
#pragma unroll
            for (int ni = 0; ni < 4; ++ni) {
                size_t m = bm + wm + mi * 16 + quad * 4;
                size_t n = bn + wn + ni * 16 + l16;
                size_t bb = m >> 11, kv = m & 2047;
                size_t hh = n >> 6,  d  = n & 63;
                u16 t4[4];
#pragma unroll
                for (int r = 0; r < 4; ++r) t4[r] = f2bf(acc[mi][ni][r]);
                *(uint2*)&C[((bb * 16 + hh) * 64 + d) * 2048 + kv] = *(const uint2*)t4;
            }
    } else {
#pragma unroll
        for (int mi = 0; mi < 4; ++mi)
#pragma unroll
            for (int ni = 0; ni < 4; ++ni)
#pragma unroll
                for (int r = 0; r < 4; ++r) {
                    size_t row = bm + wm + mi * 16 + quad * 4 + r;
                    size_t col = bn + wn + ni * 16 + l16;
                    float val = acc[mi][ni][r] * cscale;
                    if (c_bf16) ((u16*)C_)[row * N + col]   = f2bf(val);
                    else        ((float*)C_)[row * N + col] = val;
                }
    }
}

// ----------------------------------- Merged V-GEMM + K-GEMM (one dispatch)
__global__ __launch_bounds__(256, 3) void gemm128_vk(const u16* __restrict__ A0,
                                                     const u16* __restrict__ Bt0,
                                                     u16* __restrict__ C0,
                                                     const u16* __restrict__ A1,
                                                     const u16* __restrict__ Bt1,
                                                     u16* __restrict__ C1) {
    __shared__ u16 As[128 * 64];
    __shared__ u16 Bs[128 * 64];
    const int N = 1024, K = 1024, mdiv = 8;

    int id  = blockIdx.x;
    int seg = id >> 9;                 // 0 = V, 1 = K
    int lid = id & 511;
    const u16* A  = seg ? A1 : A0;
    const u16* Bt = seg ? Bt1 : Bt0;

    int j   = lid >> 3;
    int gy  = (lid & 7) + 8 * (j % mdiv);
    int bnt = j / mdiv;

    int tid  = threadIdx.x;
    int wave = tid >> 6, lane = tid & 63;
    int quad = lane >> 4, l16 = lane & 15;
    size_t bm = (size_t)gy * 128;
    size_t bn = (size_t)bnt * 128;
    int wm = (wave >> 1) * 64, wn = (wave & 1) * 64;

    int lr  = lane >> 3;
    int csw = (lane & 7) ^ lr;
    const u16* Ag = A  + (bm + wave * 32 + lr) * (size_t)K + csw * 8;
    const u16* Bg = Bt + (bn + wave * 32 + lr) * (size_t)K + csw * 8;
    u16* Al = &As[(wave * 32) * 64];
    u16* Bl = &Bs[(wave * 32) * 64];

    f32x4 acc[4][4];
#pragma unroll
    for (int i = 0; i < 4; ++i)
#pragma unroll
        for (int jj = 0; jj < 4; ++jj)
            acc[i][jj] = (f32x4){0.f, 0.f, 0.f, 0.f};

    int rsw = l16 & 7;

    for (int k0 = 0; k0 < K; k0 += 64) {
        __syncthreads();
#pragma unroll
        for (int i = 0; i < 4; ++i) {
            async16(Al + i * 8 * 64, Ag + (size_t)i * 8 * K + k0);
            async16(Bl + i * 8 * 64, Bg + (size_t)i * 8 * K + k0);
        }
        __syncthreads();

#pragma unroll
        for (int ks = 0; ks < 2; ++ks) {
            int chunk = ((ks << 2) | quad) ^ rsw;
            bf16x8 af[4], bfr[4];
#pragma unroll
            for (int mi = 0; mi < 4; ++mi)
                af[mi]  = *(const bf16x8*)&As[(wm + mi * 16 + l16) * 64 + chunk * 8];
#pragma unroll
            for (int ni = 0; ni < 4; ++ni)
                bfr[ni] = *(const bf16x8*)&Bs[(wn + ni * 16 + l16) * 64 + chunk * 8];
#pragma unroll
            for (int mi = 0; mi < 4; ++mi)
#pragma unroll
                for (int ni = 0; ni < 4; ++ni)
                    acc[mi][ni] = __builtin_amdgcn_mfma_f32_16x16x32_bf16(
                        af[mi], bfr[ni], acc[mi][ni], 0, 0, 0);
        }
    }

    if (!seg) {
        // V: transposed per-head layout [b][h][d][kv]
        u16* C = C0;
#pragma unroll
        for (int mi = 0; mi < 4; ++mi)
#pragma unroll
            for (int ni = 0; ni < 4; ++ni) {
                size_t m = bm + wm + mi * 16 + quad * 4;
                size_t n = bn + wn + ni * 16 + l16;
                size_t bb = m >> 11, kv = m & 2047;
                size_t hh = n >> 6,  d  = n & 63;
                u16 t4[4];
#pragma unroll
                for (int r = 0; r < 4; ++r) t4[r] = f2bf(acc[mi][ni][r]);
                *(uint2*)&C[((bb * 16 + hh) * 64 + d) * 2048 + kv] = *(const uint2*)t4;
            }
    } else {
        u16* C = C1;
#pragma unroll
        for (int mi = 0; mi < 4; ++mi)
#pragma unroll
            for (int ni = 0; ni < 4; ++ni)
#pragma unroll
                for (int r = 0; r < 4; ++r) {
                    size_t row = bm + wm + mi * 16 + quad * 4 + r;
                    size_t col = bn + wn + ni * 16 + l16;
                    C[row * N + col] = f2bf(acc[mi][ni][r]);
                }
    }
}

// =============================================== Q-GEMM + mask_bits merged
// Blocks [0..256): Q projection gemm (M=4096, mdiv=4, bf16 out, cscale).
// Blocks [256..1280): mask -> bit pack (bit kv == __ballot lane).
__global__ __launch_bounds__(256, 3) void qmask_kernel(const u16* __restrict__ A,
                                                       const u16* __restrict__ Bt,
                                                       u16* __restrict__ C,
                                                       float cscale,
                                                       const int* __restrict__ m,
                                                       u64* __restrict__ mb) {
    __shared__ u16 As[128 * 64];
    __shared__ u16 Bs[128 * 64];
    const int N = 1024, K = 1024, mdiv = 4;

    int blk = blockIdx.x;
    int tid = threadIdx.x;

    if (blk >= 256) {
        // ---------------- mask bits
        int mblk = blk - 256;
        int wid  = (mblk * 256 + tid) >> 6;
        int lane = tid & 63;
        size_t base = (size_t)wid * 2048;
        for (int it = 0; it < 8; ++it) {
            u64 b0 = __ballot(m[base + it * 256 +   0 + lane] == 0);
            u64 b1 = __ballot(m[base + it * 256 +  64 + lane] == 0);
            u64 b2 = __ballot(m[base + it * 256 + 128 + lane] == 0);
            u64 b3 = __ballot(m[base + it * 256 + 192 + lane] == 0);
            if (lane == 0) {
                size_t idx = (base + it * 256) >> 6;
                mb[idx + 0] = b0; mb[idx + 1] = b1; mb[idx + 2] = b2; mb[idx + 3] = b3;
            }
        }
        return;
    }

    int id  = blk;
    int j   = id >> 3;
    int gy  = (id & 7) + 8 * (j % mdiv);
    int bnt = j / mdiv;

    int wave = tid >> 6, lane = tid & 63;
    int quad = lane >> 4, l16 = lane & 15;
    size_t bm = (size_t)gy * 128;
    size_t bn = (size_t)bnt * 128;
    int wm = (wave >> 1) * 64, wn = (wave & 1) * 64;

    int lr  = lane >> 3;
    int csw = (lane & 7) ^ lr;
    const u16* Ag = A  + (bm + wave * 32 + lr) * (size_t)K + csw * 8;
    const u16* Bg = Bt + (bn + wave * 32 + lr) * (size_t)K + csw * 8;
    u16* Al = &As[(wave * 32) * 64];
    u16* Bl = &Bs[(wave * 32) * 64];

    f32x4 acc[4][4];
#pragma unroll
    for (int i = 0; i < 4; ++i)
#pragma unroll
        for (int jj = 0; jj < 4; ++jj)
            acc[i][jj] = (f32x4){0.f, 0.f, 0.f, 0.f};

    int rsw = l16 & 7;

    for (int k0 = 0; k0 < K; k0 += 64) {
        __syncthreads();
#pragma unroll
        for (int i = 0; i < 4; ++i) {
            async16(Al + i * 8 * 64, Ag + (size_t)i * 8 * K + k0);
            async16(Bl + i * 8 * 64, Bg + (size_t)i * 8 * K + k0);
        }
        __syncthreads();

#pragma unroll
        for (int ks = 0; ks < 2; ++ks) {
            int chunk = ((ks << 2) | quad) ^ rsw;
            bf16x8 af[4], bfr[4];
#pragma unroll
            for (int mi = 0; mi < 4; ++mi)
                af[mi]  = *(const bf16x8*)&As[(wm + mi * 16 + l16) * 64 + chunk * 8];
#pragma unroll
            for (int ni = 0; ni < 4; ++ni)
                bfr[ni] = *(const bf16x8*)&Bs[(wn + ni * 16 + l16) * 64 + chunk * 8];
#pragma unroll
            for (int mi = 0; mi < 4; ++mi)
#pragma unroll
                for (int ni = 0; ni < 4; ++ni)
                    acc[mi][ni] = __builtin_amdgcn_mfma_f32_16x16x32_bf16(
                        af[mi], bfr[ni], acc[mi][ni], 0, 0, 0);
        }
    }

#pragma unroll
    for (int mi = 0; mi < 4; ++mi)
#pragma unroll
        for (int ni = 0; ni < 4; ++ni)
#pragma unroll
            for (int r = 0; r < 4; ++r) {
                size_t row = bm + wm + mi * 16 + quad * 4 + r;
                size_t col = bn + wn + ni * 16 + l16;
                C[row * N + col] = f2bf(acc[mi][ni][r] * cscale);
            }
}

// ---------------------------------------------------------------- Attention
// S^T formulation, XCD-grouped, async XOR-swizzled staging, 2-way KV-split.
// Partials: per-batch 4MB chunks (o0b*/o1b*) so writes stay disjoint from reads.
__global__ __launch_bounds__(256) void attn_kernel(const u16* __restrict__ qg,
                                                   const u16* __restrict__ kg,
                                                   const u16* __restrict__ vtg,
                                                   const u32* __restrict__ mbits,
                                                   float* __restrict__ o0b0,
                                                   float* __restrict__ o0b1,
                                                   float* __restrict__ o0b2,
                                                   float* __restrict__ o0b3,
                                                   float* __restrict__ o1b0,
                                                   float* __restrict__ o1b1,
                                                   float* __restrict__ o1b2,
                                                   float* __restrict__ o1b3,
                                                   float* __restrict__ lacc0,
                                                   float* __restrict__ lacc1) {
    __shared__ u16 Ks[64 * 64];
    __shared__ u16 Vst[64 * 64];     // [d][kv], swizzled

    const int NQc = 1024, NKVc = 2048, HD = 1024;
    int id = blockIdx.x;
    int j  = id >> 3;
    int qt2 = j >> 3;                      // [0,32)
    int half = qt2 >> 4;                   // KV half
    int qt = qt2 & 15;                     // [0,16)
    int g  = (id & 7) + ((j & 7) << 3);    // [0,64) (b,h) group; xcd = id&7
    int h  = g & 15;
    int b  = g >> 4;

    int tid  = threadIdx.x;
    int wave = tid >> 6, lane = tid & 63;
    int quad = lane >> 4, l16 = lane & 15;
    int q0 = qt * 64;

    // Q fragment (B-operand: n=q=l16, k=d=quad*8+j) straight from global
    const u16* qrow = qg + ((size_t)b * NQc + q0 + wave * 16 + l16) * HD + h * 64;
    bf16x8 aq0 = *(const bf16x8*)&qrow[quad * 8];
    bf16x8 aq1 = *(const bf16x8*)&qrow[32 + quad * 8];

    // staging source addressing (per lane): row lr in 8-row group, chunk swizzle
    int lr  = lane >> 3;                   // [0,8)
    int csw = (lane & 7) ^ lr;             // source 16B chunk for phys lane&7
    const u16* kbase = kg  + ((size_t)b * NKVc + wave * 8 + lr) * HD + h * 64 + csw * 8;
    const u16* vbase = vtg + (((size_t)b * 16 + h) * 64 + wave * 8 + lr) * (size_t)NKVc + csw * 8;
    u16* kl = Ks  + (wave * 8) * 64;
    u16* vl = Vst + (wave * 8) * 64;

    f32x4 O[4], lacc;
#pragma unroll
    for (int dt = 0; dt < 4; ++dt) O[dt] = (f32x4){0.f, 0.f, 0.f, 0.f};
    lacc = (f32x4){0.f, 0.f, 0.f, 0.f};

    bf16x4 ones4;
#pragma unroll
    for (int jj = 0; jj < 4; ++jj) ones4[jj] = (short)0x3F80;

    // bit-mask row: 64 u32 per q-row, bit index == kv index
    const u32* mrowb = mbits + ((size_t)b * NQc + q0 + wave * 16 + l16) * 64;

    int l7 = l16 & 7;
    int kvbeg = half << 10;

    for (int kv0 = kvbeg; kv0 < kvbeg + 1024; kv0 += 64) {
        __syncthreads();
#pragma unroll
        for (int i = 0; i < 2; ++i) {
            // K rows kv0+i*32+wave*8+lr ; V (d-rows) i*32+wave*8+lr, cols kv0
            async16(kl + i * 32 * 64, kbase + ((size_t)kv0 + i * 32) * HD);
            async16(vl + i * 32 * 64, vbase + (size_t)(i * 32) * NKVc + kv0);
        }
        __syncthreads();

        uint2 bw = *(const uint2*)&mrowb[kv0 >> 5];   // bits kv0..kv0+63

        // per nt: S^T tile -> exp2 -> mask -> bf16x4 P^T fragment
        bf16x4 pfr[4];
#pragma unroll
        for (int nt = 0; nt < 4; ++nt) {
            const u16* krow = Ks + (nt * 16 + l16) * 64;
            bf16x8 bk0 = *(const bf16x8*)&krow[(quad ^ l7) * 8];
            bf16x8 bk1 = *(const bf16x8*)&krow[((4 + quad) ^ l7) * 8];
            f32x4 st = (f32x4){0.f, 0.f, 0.f, 0.f};
            st = __builtin_amdgcn_mfma_f32_16x16x32_bf16(bk0, aq0, st, 0, 0, 0);
            st = __builtin_amdgcn_mfma_f32_16x16x32_bf16(bk1, aq1, st, 0, 0, 0);

            u32 w  = (nt < 2) ? bw.x : bw.y;
            u32 m4 = (w >> (((nt & 1) << 4) + (quad << 2))) & 0xFu;
            u32 m01 = ((m4 & 1u) ? 0xFFFFu : 0u) | ((m4 & 2u) ? 0xFFFF0000u : 0u);
            u32 m23 = ((m4 & 4u) ? 0xFFFFu : 0u) | ((m4 & 8u) ? 0xFFFF0000u : 0u);
            u32 p01 = pkbf(fexp2(st[0]), fexp2(st[1])) & m01;
            u32 p23 = pkbf(fexp2(st[2]), fexp2(st[3])) & m23;
            uint2 pu; pu.x = p01; pu.y = p23;
            pfr[nt] = *(const bf16x4*)&pu;

            lacc = __builtin_amdgcn_mfma_f32_16x16x16bf16_1k(ones4, pfr[nt], lacc, 0, 0, 0);
        }

        // O^T += V^T . P^T   (A-frag: d-row = dt*16+l16, kv = kvs*16+quad*4)
#pragma unroll
        for (int dt = 0; dt < 4; ++dt) {
            const u16* vrow = Vst + (dt * 16 + l16) * 64;
#pragma unroll
            for (int kvs = 0; kvs < 4; ++kvs) {
                int gran = ((kvs << 1) | (quad >> 1)) ^ l7;   // 16B granule (2 per read-half)
                bf16x4 av = *(const bf16x4*)&vrow[gran * 8 + (quad & 1) * 4];
                O[dt] = __builtin_amdgcn_mfma_f32_16x16x16bf16_1k(av, pfr[kvs], O[dt], 0, 0, 0);
            }
        }
    }

    // epilogue: un-normalized f32 partials, per-batch [q][hd] layout
    int qi = q0 + wave * 16 + l16;
    float* ob;
    if (half) ob = (b == 0) ? o1b0 : (b == 1) ? o1b1 : (b == 2) ? o1b2 : o1b3;
    else      ob = (b == 0) ? o0b0 : (b == 1) ? o0b1 : (b == 2) ? o0b2 : o0b3;
    float* orow = ob + (size_t)qi * 1024 + h * 64;
#pragma unroll
    for (int dt = 0; dt < 4; ++dt)
        *(float4*)&orow[dt * 16 + quad * 4] = (float4){O[dt][0], O[dt][1], O[dt][2], O[dt][3]};

    float* lp = half ? lacc1 : lacc0;
    if (quad == 0) lp[((size_t)b * 16 + h) * 1024 + qi] = lacc[0];
}

// ------------------------------------------------------------- combine halves
__global__ __launch_bounds__(256) void combine_halves(const float* __restrict__ o0b0,
                                                      const float* __restrict__ o0b1,
                                                      const float* __restrict__ o0b2,
                                                      const float* __restrict__ o0b3,
                                                      const float* __restrict__ o1b0,
                                                      const float* __restrict__ o1b1,
                                                      const float* __restrict__ o1b2,
                                                      const float* __restrict__ o1b3,
                                                      const float* __restrict__ l0,
                                                      const float* __restrict__ l1,
                                                      u16* __restrict__ ao) {
    int row = blockIdx.x;                 // b*1024 + q
    int b = row >> 10, qq = row & 1023;
    const float* p0 = (b == 0) ? o0b0 : (b == 1) ? o0b1 : (b == 2) ? o0b2 : o0b3;
    const float* p1 = (b == 0) ? o1b0 : (b == 1) ? o1b1 : (b == 2) ? o1b2 : o1b3;
    int tid = threadIdx.x;
    int hd = tid * 4;
    int h  = hd >> 6;
    float4 a = *(const float4*)&p0[(size_t)qq * 1024 + hd];
    float4 c = *(const float4*)&p1[(size_t)qq * 1024 + hd];
    size_t li = ((size_t)b * 16 + h) * 1024 + qq;
    float inv = 1.0f / (l0[li] + l1[li]);
    uint2 o;
    o.x = (u32)f2bf((a.x + c.x) * inv) | ((u32)f2bf((a.y + c.y) * inv) << 16);
    o.y = (u32)f2bf((a.z + c.z) * inv) | ((u32)f2bf((a.w + c.w) * inv) << 16);
    *(uint2*)&ao[(size_t)row * 1024 + hd] = o;
}

// ---------------------------------------------------------------- launch
extern "C" void kernel_launch(void* const* d_in, const int* in_sizes, int n_in,
                              void* d_out, int out_size, void* d_ws, size_t ws_size,
                              hipStream_t stream) {
    const void* x     = d_in[0];
    const void* key   = d_in[1];
    const void* value = d_in[2];
    const int*  mask  = (const int*)d_in[3];
    const void* Wq    = d_in[4];
    const void* Wk    = d_in[5];
    const void* Wv    = d_in[6];
    const void* Wo    = d_in[7];
    const void* gamma = d_in[8];
    const void* beta  = d_in[9];

    // ws layout (65 MB), time-multiplexed (all concurrent uses disjoint):
    //  @0   flag
    //  @1   xn [8MB] (prep out; Q in)       -> after Q: o0b0@1..5, o0b1@5..9
    //  @9   kb [16MB] (prep out; K in)      -> after VK: mbits@9..10, o0b2@10..14,
    //                                          o0b3@14..18, o1b0@18..22, la@22..22.5
    //  @25  vb [16MB] (prep out; V in)      -> after VK: q@25..33, o1b2@33..37,
    //                                          o1b3@37..41
    //  @41  vT [16MB] (VK out; attn in)     -> after attn: ao@41..49
    //  @57  Wqt@57, Wkt@59, Wvt@61, Wot@63  -> after VK: o1b1@59..63 (Wkt/Wvt dead;
    //                                          Wot@63..65 preserved for final gemm)
    //  k (16MB bf16) lives in d_out until the final gemm overwrites it.
    char* ws = (char*)d_ws;
    int* flag   = (int*)(ws);
    u16* xn     = (u16*)(ws + ( 1ull << 20));
    float* o0b0 = (float*)(ws + ( 1ull << 20));
    float* o0b1 = (float*)(ws + ( 5ull << 20));
    u16* kb     = (u16*)(ws + ( 9ull << 20));
    u32* mbits  = (u32*)(ws + ( 9ull << 20));
    float* o0b2 = (float*)(ws + (10ull << 20));
    float* o0b3 = (float*)(ws + (14ull << 20));
    float* o1b0 = (float*)(ws + (18ull << 20));
    float* la0  = (float*)(ws + (22ull << 20));
    float* la1  = (float*)(ws + (22ull << 20) + (256ull << 10));
    u16* vb     = (u16*)(ws + (25ull << 20));
    u16* q      = (u16*)(ws + (25ull << 20));
    float* o1b2 = (float*)(ws + (33ull << 20));
    float* o1b3 = (float*)(ws + (37ull << 20));
    u16* vT     = (u16*)(ws + (41ull << 20));
    u16* ao     = (u16*)(ws + (41ull << 20));
    u16* Wqt    = (u16*)(ws + (57ull << 20));
    u16* Wkt    = (u16*)(ws + (59ull << 20));
    float* o1b1 = (float*)(ws + (59ull << 20));
    u16* Wvt    = (u16*)(ws + (61ull << 20));
    u16* Wot    = (u16*)(ws + (63ull << 20));
    u16* k      = (u16*)d_out;

    const float QSCALE = 0.125f * 1.44269504f;   // d^-0.5 * log2(e) for exp2 softmax

    // prep: detect + LN + weight transpose + K/V convert, one dispatch
    prep_kernel<<<13313, 256, 0, stream>>>((const u32*)x, x, key, value,
                                           gamma, beta, Wq, Wk, Wv, Wo,
                                           xn, kb, vb, Wqt, Wkt, Wvt, Wot, flag);

    // merged V+K gemm: 1024 blocks, 3 blocks/CU
    gemm128_vk<<<1024, 256, 0, stream>>>(vb, Wvt, vT, kb, Wkt, k);

    // Q-gemm + mask bit-pack, one dispatch (vb/kb dead; Wqt still live for Q)
    qmask_kernel<<<1280, 256, 0, stream>>>(xn, Wqt, q, QSCALE, mask, (u64*)mbits);

    attn_kernel<<<2048, 256, 0, stream>>>(q, k, vT, mbits,
                                          o0b0, o0b1, o0b2, o0b3,
                                          o1b0, o1b1, o1b2, o1b3, la0, la1);

    combine_halves<<<4096, 256, 0, stream>>>(o0b0, o0b1, o0b2, o0b3,
                                             o1b0, o1b1, o1b2, o1b3,
                                             la0, la1, ao);

    gemm128<<<256, 256, 0, stream>>>(ao, Wot, d_out, 4096, 1024, 1024, flag, 1, 1.0f, 0, 4);
}

// Round 8
// 320.077 us; speedup vs baseline: 1.2401x; 1.0646x over previous
//
#include <hip/hip_runtime.h>

typedef unsigned short u16;
typedef unsigned int u32;
typedef unsigned char u8;
typedef unsigned long long u64;

typedef __attribute__((ext_vector_type(8))) short bf16x8;
typedef __attribute__((ext_vector_type(4))) short bf16x4;
typedef __attribute__((ext_vector_type(4))) float f32x4;

__device__ __forceinline__ float bf2f(u16 u) {
    union { u32 i; float f; } v; v.i = ((u32)u) << 16; return v.f;
}
__device__ __forceinline__ u16 f2bf(float f) {
    union { float f; u32 i; } v; v.f = f;
    u32 r = v.i + 0x7fffu + ((v.i >> 16) & 1u);
    return (u16)(r >> 16);
}
// pack two f32 -> bf16x2 in one u32 (low = a, high = b) — software RNE (proven)
__device__ __forceinline__ u32 pkbf(float a, float b) {
    return (u32)f2bf(a) | ((u32)f2bf(b) << 16);
}
// raw v_exp_f32 (2^x). <=2 ULP vs OCML exp2f — negligible for softmax P.
__device__ __forceinline__ float fexp2(float x) { return __builtin_amdgcn_exp2f(x); }

// async global->LDS, 16B per lane; lds must be wave-uniform (lane*16 added by HW)
__device__ __forceinline__ void async16(u16* lds, const u16* g) {
    __builtin_amdgcn_global_load_lds(
        (const __attribute__((address_space(1))) void*)g,
        (__attribute__((address_space(3))) void*)lds, 16, 0, 0);
}

// =============================================================== PREP
// One dispatch: [0..4096) LayerNorm rows, [4096..5120) weight transpose,
// [5120..13312) key/value bf16 convert, block 13312 writes flag.
// Every block self-detects dtype on x's first 4KB (identical words+threshold
// as the old detect_dtype kernel -> bit-identical decision; L2-broadcast).
__global__ __launch_bounds__(256) void prep_kernel(
        const u32* __restrict__ xw,          // x as words (for detect)
        const void* __restrict__ x_,
        const void* __restrict__ key,
        const void* __restrict__ value,
        const void* __restrict__ g_,
        const void* __restrict__ b_,
        const void* __restrict__ Wq, const void* __restrict__ Wk,
        const void* __restrict__ Wv, const void* __restrict__ Wo,
        u16* __restrict__ xn,
        u16* __restrict__ kb, u16* __restrict__ vb,
        u16* __restrict__ Wqt, u16* __restrict__ Wkt,
        u16* __restrict__ Wvt, u16* __restrict__ Wot,
        int* __restrict__ flagp) {
    __shared__ int  redi[4];
    __shared__ float redf[8];
    __shared__ u16 tsh[64][65];

    int tid = threadIdx.x;
    int wave = tid >> 6, lane = tid & 63;

    // --- self-detect on x[0..1023] words (matches old detect_dtype exactly)
    int hits = 0;
    for (int i = 0; i < 4; ++i) {
        u32 w = xw[tid * 4 + i];
        u32 e = (w >> 7) & 0xFFu;
        hits += (e >= 110u && e <= 131u) ? 1 : 0;
    }
    for (int off = 1; off < 64; off <<= 1) hits += __shfl_xor(hits, off, 64);
    if (lane == 0) redi[wave] = hits;
    __syncthreads();
    int flag = (redi[0] + redi[1] + redi[2] + redi[3] > 512) ? 1 : 0;

    int blk = blockIdx.x;

    if (blk == 13312) {                       // flag writer for later gemms
        if (tid == 0) flagp[0] = flag;
        return;
    }

    if (blk < 4096) {
        // ---------------- LayerNorm row
        int row = blk;
        float v[4];
        if (flag) {
            const u16* xr = (const u16*)x_ + (size_t)row * 1024;
            uint2 d = *(const uint2*)&xr[tid * 4];
            v[0] = bf2f((u16)(d.x & 0xffff));
            v[1] = bf2f((u16)(d.x >> 16));
            v[2] = bf2f((u16)(d.y & 0xffff));
            v[3] = bf2f((u16)(d.y >> 16));
        } else {
            const float* xr = (const float*)x_ + (size_t)row * 1024;
            float4 d = *(const float4*)&xr[tid * 4];
            v[0] = d.x; v[1] = d.y; v[2] = d.z; v[3] = d.w;
        }
        float s  = v[0] + v[1] + v[2] + v[3];
        float ss = v[0]*v[0] + v[1]*v[1] + v[2]*v[2] + v[3]*v[3];
        for (int off = 1; off < 64; off <<= 1) {
            s  += __shfl_xor(s,  off, 64);
            ss += __shfl_xor(ss, off, 64);
        }
        if (lane == 0) { redf[wave] = s; redf[4 + wave] = ss; }
        __syncthreads();
        s  = redf[0] + redf[1] + redf[2] + redf[3];
        ss = redf[4] + redf[5] + redf[6] + redf[7];
        float mu   = s * (1.0f / 1024.0f);
        float var  = ss * (1.0f / 1024.0f) - mu * mu;
        float rstd = rsqrtf(var + 1e-5f);
        u16 r01[4];
        for (int j = 0; j < 4; ++j) {
            float g, bb;
            if (flag) { g = bf2f(((const u16*)g_)[tid * 4 + j]); bb = bf2f(((const u16*)b_)[tid * 4 + j]); }
            else      { g = ((const float*)g_)[tid * 4 + j];     bb = ((const float*)b_)[tid * 4 + j]; }
            r01[j] = f2bf((v[j] - mu) * rstd * g + bb);
        }
        uint2 o;
        o.x = (u32)r01[0] | ((u32)r01[1] << 16);
        o.y = (u32)r01[2] | ((u32)r01[3] << 16);
        *(uint2*)&xn[(size_t)row * 1024 + tid * 4] = o;
    } else if (blk < 5120) {
        // ---------------- weight transpose (64x64 tile)
        int t = blk - 4096;
        int w = t >> 8;                       // which weight
        int tt = t & 255;
        const void* src_ = (w == 0) ? Wq : (w == 1) ? Wk : (w == 2) ? Wv : Wo;
        u16* dst = (w == 0) ? Wqt : (w == 1) ? Wkt : (w == 2) ? Wvt : Wot;
        int bx = (tt & 15) * 64;
        int by = (tt >> 4) * 64;
        const int rows = 1024, cols = 1024;
        for (int i = 0; i < 16; ++i) {
            int r = i * 4 + (tid >> 6);
            int c = tid & 63;
            size_t idx = (size_t)(by + r) * cols + bx + c;
            tsh[r][c] = flag ? ((const u16*)src_)[idx] : f2bf(((const float*)src_)[idx]);
        }
        __syncthreads();
        for (int i = 0; i < 16; ++i) {
            int r = i * 4 + (tid >> 6);
            int c = tid & 63;
            dst[(size_t)(bx + r) * rows + by + c] = tsh[c][r];
        }
    } else {
        // ---------------- key/value -> bf16
        int cblk = blk - 5120;
        const void* src = (cblk < 4096) ? key : value;
        u16* dst = (cblk < 4096) ? kb : vb;
        int b2 = (cblk < 4096) ? cblk : (cblk - 4096);
        size_t i = (size_t)b2 * 256 + tid;
        if (flag) {
            ((uint4*)dst)[i] = ((const uint4*)src)[i];
        } else {
            const float4* s4 = (const float4*)src + i * 2;
            float4 f0 = s4[0], f1 = s4[1];
            u16 t8[8];
            t8[0] = f2bf(f0.x); t8[1] = f2bf(f0.y); t8[2] = f2bf(f0.z); t8[3] = f2bf(f0.w);
            t8[4] = f2bf(f1.x); t8[5] = f2bf(f1.y); t8[6] = f2bf(f1.z); t8[7] = f2bf(f1.w);
            ((uint4*)dst)[i] = *(const uint4*)t8;
        }
    }
}

// ----------------------------------- Merged V-GEMM + K-GEMM (one dispatch)
__global__ __launch_bounds__(256, 3) void gemm128_vk(const u16* __restrict__ A0,
                                                     const u16* __restrict__ Bt0,
                                                     u16* __restrict__ C0,
                                                     const u16* __restrict__ A1,
                                                     const u16* __restrict__ Bt1,
                                                     u16* __restrict__ C1) {
    __shared__ u16 As[128 * 64];
    __shared__ u16 Bs[128 * 64];
    const int N = 1024, K = 1024, mdiv = 8;

    int id  = blockIdx.x;
    int seg = id >> 9;                 // 0 = V, 1 = K
    int lid = id & 511;
    const u16* A  = seg ? A1 : A0;
    const u16* Bt = seg ? Bt1 : Bt0;

    int j   = lid >> 3;
    int gy  = (lid & 7) + 8 * (j % mdiv);
    int bnt = j / mdiv;

    int tid  = threadIdx.x;
    int wave = tid >> 6, lane = tid & 63;
    int quad = lane >> 4, l16 = lane & 15;
    size_t bm = (size_t)gy * 128;
    size_t bn = (size_t)bnt * 128;
    int wm = (wave >> 1) * 64, wn = (wave & 1) * 64;

    int lr  = lane >> 3;
    int csw = (lane & 7) ^ lr;
    const u16* Ag = A  + (bm + wave * 32 + lr) * (size_t)K + csw * 8;
    const u16* Bg = Bt + (bn + wave * 32 + lr) * (size_t)K + csw * 8;
    u16* Al = &As[(wave * 32) * 64];
    u16* Bl = &Bs[(wave * 32) * 64];

    f32x4 acc[4][4];
#pragma unroll
    for (int i = 0; i < 4; ++i)
#pragma unroll
        for (int jj = 0; jj < 4; ++jj)
            acc[i][jj] = (f32x4){0.f, 0.f, 0.f, 0.f};

    int rsw = l16 & 7;

    for (int k0 = 0; k0 < K; k0 += 64) {
        __syncthreads();
#pragma unroll
        for (int i = 0; i < 4; ++i) {
            async16(Al + i * 8 * 64, Ag + (size_t)i * 8 * K + k0);
            async16(Bl + i * 8 * 64, Bg + (size_t)i * 8 * K + k0);
        }
        __syncthreads();

#pragma unroll
        for (int ks = 0; ks < 2; ++ks) {
            int chunk = ((ks << 2) | quad) ^ rsw;
            bf16x8 af[4], bfr[4];
#pragma unroll
            for (int mi = 0; mi < 4; ++mi)
                af[mi]  = *(const bf16x8*)&As[(wm + mi * 16 + l16) * 64 + chunk * 8];
#pragma unroll
            for (int ni = 0; ni < 4; ++ni)
                bfr[ni] = *(const bf16x8*)&Bs[(wn + ni * 16 + l16) * 64 + chunk * 8];
#pragma unroll
            for (int mi = 0; mi < 4; ++mi)
#pragma unroll
                for (int ni = 0; ni < 4; ++ni)
                    acc[mi][ni] = __builtin_amdgcn_mfma_f32_16x16x32_bf16(
                        af[mi], bfr[ni], acc[mi][ni], 0, 0, 0);
        }
    }

    if (!seg) {
        // V: transposed per-head layout [b][h][d][kv]
        u16* C = C0;
#pragma unroll
        for (int mi = 0; mi < 4; ++mi)
#pragma unroll
            for (int ni = 0; ni < 4; ++ni) {
                size_t m = bm + wm + mi * 16 + quad * 4;
                size_t n = bn + wn + ni * 16 + l16;
                size_t bb = m >> 11, kv = m & 2047;
                size_t hh = n >> 6,  d  = n & 63;
                u16 t4[4];
#pragma unroll
                for (int r = 0; r < 4; ++r) t4[r] = f2bf(acc[mi][ni][r]);
                *(uint2*)&C[((bb * 16 + hh) * 64 + d) * 2048 + kv] = *(const uint2*)t4;
            }
    } else {
        u16* C = C1;
#pragma unroll
        for (int mi = 0; mi < 4; ++mi)
#pragma unroll
            for (int ni = 0; ni < 4; ++ni)
#pragma unroll
                for (int r = 0; r < 4; ++r) {
                    size_t row = bm + wm + mi * 16 + quad * 4 + r;
                    size_t col = bn + wn + ni * 16 + l16;
                    C[row * N + col] = f2bf(acc[mi][ni][r]);
                }
    }
}

// ================================= GEMM 64x128 tile body (M=4096 shapes)
// Half-M tile doubles grid (256 -> 512 blocks) for the occupancy-starved
// Q/O gemms. Same swizzle/fragment formulas as gemm128 with wm in {0,32},
// acc[2][4]; A-tile 64 rows (2 async16 calls), B-tile 128 rows (4 calls).
__device__ __forceinline__ void gemm64_body(u16* As, u16* Bs,
                                            const u16* __restrict__ A,
                                            const u16* __restrict__ Bt,
                                            void* __restrict__ C_,
                                            int flag, int c_flagged, float cscale,
                                            int lid) {
    const int N = 1024, K = 1024, mdiv = 8;   // M = 4096 -> 64 m-tiles
    bool c_bf16 = c_flagged ? (flag != 0) : true;

    int j   = lid >> 3;
    int gy  = (lid & 7) + 8 * (j % mdiv);
    int bnt = j / mdiv;

    int tid  = threadIdx.x;
    int wave = tid >> 6, lane = tid & 63;
    int quad = lane >> 4, l16 = lane & 15;
    size_t bm = (size_t)gy * 64;
    size_t bn = (size_t)bnt * 128;
    int wm = (wave >> 1) * 32, wn = (wave & 1) * 64;

    int lr  = lane >> 3;
    int csw = (lane & 7) ^ lr;
    const u16* Ag = A  + (bm + wave * 8 + lr) * (size_t)K + csw * 8;
    const u16* Bg = Bt + (bn + wave * 8 + lr) * (size_t)K + csw * 8;
    u16* Al = &As[(wave * 8) * 64];
    u16* Bl = &Bs[(wave * 8) * 64];

    f32x4 acc[2][4];
#pragma unroll
    for (int i = 0; i < 2; ++i)
#pragma unroll
        for (int jj = 0; jj < 4; ++jj)
            acc[i][jj] = (f32x4){0.f, 0.f, 0.f, 0.f};

    int rsw = l16 & 7;

    for (int k0 = 0; k0 < K; k0 += 64) {
        __syncthreads();
#pragma unroll
        for (int i = 0; i < 2; ++i)
            async16(Al + i * 32 * 64, Ag + (size_t)i * 32 * K + k0);
#pragma unroll
        for (int i = 0; i < 4; ++i)
            async16(Bl + i * 32 * 64, Bg + (size_t)i * 32 * K + k0);
        __syncthreads();

#pragma unroll
        for (int ks = 0; ks < 2; ++ks) {
            int chunk = ((ks << 2) | quad) ^ rsw;
            bf16x8 af[2], bfr[4];
#pragma unroll
            for (int mi = 0; mi < 2; ++mi)
                af[mi]  = *(const bf16x8*)&As[(wm + mi * 16 + l16) * 64 + chunk * 8];
#pragma unroll
            for (int ni = 0; ni < 4; ++ni)
                bfr[ni] = *(const bf16x8*)&Bs[(wn + ni * 16 + l16) * 64 + chunk * 8];
#pragma unroll
            for (int mi = 0; mi < 2; ++mi)
#pragma unroll
                for (int ni = 0; ni < 4; ++ni)
                    acc[mi][ni] = __builtin_amdgcn_mfma_f32_16x16x32_bf16(
                        af[mi], bfr[ni], acc[mi][ni], 0, 0, 0);
        }
    }

#pragma unroll
    for (int mi = 0; mi < 2; ++mi)
#pragma unroll
        for (int ni = 0; ni < 4; ++ni)
#pragma unroll
            for (int r = 0; r < 4; ++r) {
                size_t row = bm + wm + mi * 16 + quad * 4 + r;
                size_t col = bn + wn + ni * 16 + l16;
                float val = acc[mi][ni][r] * cscale;
                if (c_bf16) ((u16*)C_)[row * N + col]   = f2bf(val);
                else        ((float*)C_)[row * N + col] = val;
            }
}

// =============================================== Q-GEMM (64-tile) + mask_bits
// Blocks [0..512): Q projection gemm (M=4096, bf16 out, cscale).
// Blocks [512..1536): mask -> bit pack (bit kv == __ballot lane).
__global__ __launch_bounds__(256, 3) void qmask_kernel(const u16* __restrict__ A,
                                                       const u16* __restrict__ Bt,
                                                       u16* __restrict__ C,
                                                       float cscale,
                                                       const int* __restrict__ m,
                                                       u64* __restrict__ mb) {
    __shared__ u16 As[64 * 64];
    __shared__ u16 Bs[128 * 64];

    int blk = blockIdx.x;
    int tid = threadIdx.x;

    if (blk >= 512) {
        // ---------------- mask bits
        int mblk = blk - 512;
        int wid  = (mblk * 256 + tid) >> 6;
        int lane = tid & 63;
        size_t base = (size_t)wid * 2048;
        for (int it = 0; it < 8; ++it) {
            u64 b0 = __ballot(m[base + it * 256 +   0 + lane] == 0);
            u64 b1 = __ballot(m[base + it * 256 +  64 + lane] == 0);
            u64 b2 = __ballot(m[base + it * 256 + 128 + lane] == 0);
            u64 b3 = __ballot(m[base + it * 256 + 192 + lane] == 0);
            if (lane == 0) {
                size_t idx = (base + it * 256) >> 6;
                mb[idx + 0] = b0; mb[idx + 1] = b1; mb[idx + 2] = b2; mb[idx + 3] = b3;
            }
        }
        return;
    }

    gemm64_body(As, Bs, A, Bt, (void*)C, 1, 0, cscale, blk);
}

// =============================================== O-GEMM (64-tile, flag out)
__global__ __launch_bounds__(256, 3) void ogemm64(const u16* __restrict__ A,
                                                  const u16* __restrict__ Bt,
                                                  void* __restrict__ C_,
                                                  const int* __restrict__ flagp) {
    __shared__ u16 As[64 * 64];
    __shared__ u16 Bs[128 * 64];
    int flag = *flagp;
    gemm64_body(As, Bs, A, Bt, C_, flag, 1, 1.0f, blockIdx.x);
}

// ---------------------------------------------------------------- Attention
// S^T formulation, XCD-grouped, async XOR-swizzled staging, 2-way KV-split.
// Partials: per-batch 4MB chunks (o0b*/o1b*) so writes stay disjoint from reads.
__global__ __launch_bounds__(256) void attn_kernel(const u16* __restrict__ qg,
                                                   const u16* __restrict__ kg,
                                                   const u16* __restrict__ vtg,
                                                   const u32* __restrict__ mbits,
                                                   float* __restrict__ o0b0,
                                                   float* __restrict__ o0b1,
                                                   float* __restrict__ o0b2,
                                                   float* __restrict__ o0b3,
                                                   float* __restrict__ o1b0,
                                                   float* __restrict__ o1b1,
                                                   float* __restrict__ o1b2,
                                                   float* __restrict__ o1b3,
                                                   float* __restrict__ lacc0,
                                                   float* __restrict__ lacc1) {
    __shared__ u16 Ks[64 * 64];
    __shared__ u16 Vst[64 * 64];     // [d][kv], swizzled

    const int NQc = 1024, NKVc = 2048, HD = 1024;
    int id = blockIdx.x;
    int j  = id >> 3;
    int qt2 = j >> 3;                      // [0,32)
    int half = qt2 >> 4;                   // KV half
    int qt = qt2 & 15;                     // [0,16)
    int g  = (id & 7) + ((j & 7) << 3);    // [0,64) (b,h) group; xcd = id&7
    int h  = g & 15;
    int b  = g >> 4;

    int tid  = threadIdx.x;
    int wave = tid >> 6, lane = tid & 63;
    int quad = lane >> 4, l16 = lane & 15;
    int q0 = qt * 64;

    // Q fragment (B-operand: n=q=l16, k=d=quad*8+j) straight from global
    const u16* qrow = qg + ((size_t)b * NQc + q0 + wave * 16 + l16) * HD + h * 64;
    bf16x8 aq0 = *(const bf16x8*)&qrow[quad * 8];
    bf16x8 aq1 = *(const bf16x8*)&qrow[32 + quad * 8];

    // staging source addressing (per lane): row lr in 8-row group, chunk swizzle
    int lr  = lane >> 3;                   // [0,8)
    int csw = (lane & 7) ^ lr;             // source 16B chunk for phys lane&7
    const u16* kbase = kg  + ((size_t)b * NKVc + wave * 8 + lr) * HD + h * 64 + csw * 8;
    const u16* vbase = vtg + (((size_t)b * 16 + h) * 64 + wave * 8 + lr) * (size_t)NKVc + csw * 8;
    u16* kl = Ks  + (wave * 8) * 64;
    u16* vl = Vst + (wave * 8) * 64;

    f32x4 O[4], lacc;
#pragma unroll
    for (int dt = 0; dt < 4; ++dt) O[dt] = (f32x4){0.f, 0.f, 0.f, 0.f};
    lacc = (f32x4){0.f, 0.f, 0.f, 0.f};

    bf16x4 ones4;
#pragma unroll
    for (int jj = 0; jj < 4; ++jj) ones4[jj] = (short)0x3F80;

    // bit-mask row: 64 u32 per q-row, bit index == kv index
    const u32* mrowb = mbits + ((size_t)b * NQc + q0 + wave * 16 + l16) * 64;

    int l7 = l16 & 7;
    int kvbeg = half << 10;

    for (int kv0 = kvbeg; kv0 < kvbeg + 1024; kv0 += 64) {
        __syncthreads();
#pragma unroll
        for (int i = 0; i < 2; ++i) {
            // K rows kv0+i*32+wave*8+lr ; V (d-rows) i*32+wave*8+lr, cols kv0
            async16(kl + i * 32 * 64, kbase + ((size_t)kv0 + i * 32) * HD);
            async16(vl + i * 32 * 64, vbase + (size_t)(i * 32) * NKVc + kv0);
        }
        __syncthreads();

        uint2 bw = *(const uint2*)&mrowb[kv0 >> 5];   // bits kv0..kv0+63

        // per nt: S^T tile -> exp2 -> mask -> bf16x4 P^T fragment
        bf16x4 pfr[4];
#pragma unroll
        for (int nt = 0; nt < 4; ++nt) {
            const u16* krow = Ks + (nt * 16 + l16) * 64;
            bf16x8 bk0 = *(const bf16x8*)&krow[(quad ^ l7) * 8];
            bf16x8 bk1 = *(const bf16x8*)&krow[((4 + quad) ^ l7) * 8];
            f32x4 st = (f32x4){0.f, 0.f, 0.f, 0.f};
            st = __builtin_amdgcn_mfma_f32_16x16x32_bf16(bk0, aq0, st, 0, 0, 0);
            st = __builtin_amdgcn_mfma_f32_16x16x32_bf16(bk1, aq1, st, 0, 0, 0);

            u32 w  = (nt < 2) ? bw.x : bw.y;
            u32 m4 = (w >> (((nt & 1) << 4) + (quad << 2))) & 0xFu;
            u32 m01 = ((m4 & 1u) ? 0xFFFFu : 0u) | ((m4 & 2u) ? 0xFFFF0000u : 0u);
            u32 m23 = ((m4 & 4u) ? 0xFFFFu : 0u) | ((m4 & 8u) ? 0xFFFF0000u : 0u);
            u32 p01 = pkbf(fexp2(st[0]), fexp2(st[1])) & m01;
            u32 p23 = pkbf(fexp2(st[2]), fexp2(st[3])) & m23;
            uint2 pu; pu.x = p01; pu.y = p23;
            pfr[nt] = *(const bf16x4*)&pu;

            lacc = __builtin_amdgcn_mfma_f32_16x16x16bf16_1k(ones4, pfr[nt], lacc, 0, 0, 0);
        }

        // O^T += V^T . P^T   (A-frag: d-row = dt*16+l16, kv = kvs*16+quad*4)
#pragma unroll
        for (int dt = 0; dt < 4; ++dt) {
            const u16* vrow = Vst + (dt * 16 + l16) * 64;
#pragma unroll
            for (int kvs = 0; kvs < 4; ++kvs) {
                int gran = ((kvs << 1) | (quad >> 1)) ^ l7;   // 16B granule (2 per read-half)
                bf16x4 av = *(const bf16x4*)&vrow[gran * 8 + (quad & 1) * 4];
                O[dt] = __builtin_amdgcn_mfma_f32_16x16x16bf16_1k(av, pfr[kvs], O[dt], 0, 0, 0);
            }
        }
    }

    // epilogue: un-normalized f32 partials, per-batch [q][hd] layout
    int qi = q0 + wave * 16 + l16;
    float* ob;
    if (half) ob = (b == 0) ? o1b0 : (b == 1) ? o1b1 : (b == 2) ? o1b2 : o1b3;
    else      ob = (b == 0) ? o0b0 : (b == 1) ? o0b1 : (b == 2) ? o0b2 : o0b3;
    float* orow = ob + (size_t)qi * 1024 + h * 64;
#pragma unroll
    for (int dt = 0; dt < 4; ++dt)
        *(float4*)&orow[dt * 16 + quad * 4] = (float4){O[dt][0], O[dt][1], O[dt][2], O[dt][3]};

    float* lp = half ? lacc1 : lacc0;
    if (quad == 0) lp[((size_t)b * 16 + h) * 1024 + qi] = lacc[0];
}

// ------------------------------------------------------------- combine halves
__global__ __launch_bounds__(256) void combine_halves(const float* __restrict__ o0b0,
                                                      const float* __restrict__ o0b1,
                                                      const float* __restrict__ o0b2,
                                                      const float* __restrict__ o0b3,
                                                      const float* __restrict__ o1b0,
                                                      const float* __restrict__ o1b1,
                                                      const float* __restrict__ o1b2,
                                                      const float* __restrict__ o1b3,
                                                      const float* __restrict__ l0,
                                                      const float* __restrict__ l1,
                                                      u16* __restrict__ ao) {
    int row = blockIdx.x;                 // b*1024 + q
    int b = row >> 10, qq = row & 1023;
    const float* p0 = (b == 0) ? o0b0 : (b == 1) ? o0b1 : (b == 2) ? o0b2 : o0b3;
    const float* p1 = (b == 0) ? o1b0 : (b == 1) ? o1b1 : (b == 2) ? o1b2 : o1b3;
    int tid = threadIdx.x;
    int hd = tid * 4;
    int h  = hd >> 6;
    float4 a = *(const float4*)&p0[(size_t)qq * 1024 + hd];
    float4 c = *(const float4*)&p1[(size_t)qq * 1024 + hd];
    size_t li = ((size_t)b * 16 + h) * 1024 + qq;
    float inv = 1.0f / (l0[li] + l1[li]);
    uint2 o;
    o.x = (u32)f2bf((a.x + c.x) * inv) | ((u32)f2bf((a.y + c.y) * inv) << 16);
    o.y = (u32)f2bf((a.z + c.z) * inv) | ((u32)f2bf((a.w + c.w) * inv) << 16);
    *(uint2*)&ao[(size_t)row * 1024 + hd] = o;
}

// ---------------------------------------------------------------- launch
extern "C" void kernel_launch(void* const* d_in, const int* in_sizes, int n_in,
                              void* d_out, int out_size, void* d_ws, size_t ws_size,
                              hipStream_t stream) {
    const void* x     = d_in[0];
    const void* key   = d_in[1];
    const void* value = d_in[2];
    const int*  mask  = (const int*)d_in[3];
    const void* Wq    = d_in[4];
    const void* Wk    = d_in[5];
    const void* Wv    = d_in[6];
    const void* Wo    = d_in[7];
    const void* gamma = d_in[8];
    const void* beta  = d_in[9];

    // ws layout (65 MB), time-multiplexed (all concurrent uses disjoint):
    //  @0   flag
    //  @1   xn [8MB] (prep out; Q in)       -> after Q: o0b0@1..5, o0b1@5..9
    //  @9   kb [16MB] (prep out; K in)      -> after VK: mbits@9..10, o0b2@10..14,
    //                                          o0b3@14..18, o1b0@18..22, la@22..22.5
    //  @25  vb [16MB] (prep out; V in)      -> after VK: q@25..33, o1b2@33..37,
    //                                          o1b3@37..41
    //  @41  vT [16MB] (VK out; attn in)     -> after attn: ao@41..49
    //  @57  Wqt@57, Wkt@59, Wvt@61, Wot@63  -> after VK: o1b1@59..63 (Wkt/Wvt dead;
    //                                          Wot@63..65 preserved for final gemm)
    //  k (16MB bf16) lives in d_out until the final gemm overwrites it.
    char* ws = (char*)d_ws;
    int* flag   = (int*)(ws);
    u16* xn     = (u16*)(ws + ( 1ull << 20));
    float* o0b0 = (float*)(ws + ( 1ull << 20));
    float* o0b1 = (float*)(ws + ( 5ull << 20));
    u16* kb     = (u16*)(ws + ( 9ull << 20));
    u32* mbits  = (u32*)(ws + ( 9ull << 20));
    float* o0b2 = (float*)(ws + (10ull << 20));
    float* o0b3 = (float*)(ws + (14ull << 20));
    float* o1b0 = (float*)(ws + (18ull << 20));
    float* la0  = (float*)(ws + (22ull << 20));
    float* la1  = (float*)(ws + (22ull << 20) + (256ull << 10));
    u16* vb     = (u16*)(ws + (25ull << 20));
    u16* q      = (u16*)(ws + (25ull << 20));
    float* o1b2 = (float*)(ws + (33ull << 20));
    float* o1b3 = (float*)(ws + (37ull << 20));
    u16* vT     = (u16*)(ws + (41ull << 20));
    u16* ao     = (u16*)(ws + (41ull << 20));
    u16* Wqt    = (u16*)(ws + (57ull << 20));
    u16* Wkt    = (u16*)(ws + (59ull << 20));
    float* o1b1 = (float*)(ws + (59ull << 20));
    u16* Wvt    = (u16*)(ws + (61ull << 20));
    u16* Wot    = (u16*)(ws + (63ull << 20));
    u16* k      = (u16*)d_out;

    const float QSCALE = 0.125f * 1.44269504f;   // d^-0.5 * log2(e) for exp2 softmax

    // prep: detect + LN + weight transpose + K/V convert, one dispatch
    prep_kernel<<<13313, 256, 0, stream>>>((const u32*)x, x, key, value,
                                           gamma, beta, Wq, Wk, Wv, Wo,
                                           xn, kb, vb, Wqt, Wkt, Wvt, Wot, flag);

    // merged V+K gemm: 1024 blocks, 3 blocks/CU
    gemm128_vk<<<1024, 256, 0, stream>>>(vb, Wvt, vT, kb, Wkt, k);

    // Q-gemm (64-tile, 512 blocks) + mask bit-pack, one dispatch
    qmask_kernel<<<1536, 256, 0, stream>>>(xn, Wqt, q, QSCALE, mask, (u64*)mbits);

    attn_kernel<<<2048, 256, 0, stream>>>(q, k, vT, mbits,
                                          o0b0, o0b1, o0b2, o0b3,
                                          o1b0, o1b1, o1b2, o1b3, la0, la1);

    combine_halves<<<4096, 256, 0, stream>>>(o0b0, o0b1, o0b2, o0b3,
                                             o1b0, o1b1, o1b2, o1b3,
                                             la0, la1, ao);

    // O-gemm (64-tile, 512 blocks)
    ogemm64<<<512, 256, 0, stream>>>(ao, Wot, d_out, flag);
}